// Round 5
// baseline (280.979 us; speedup 1.0000x reference)
//
#include <hip/hip_runtime.h>
#include <math.h>

#define BATCH 4
#define NPTS  2048
#define PTS   8192      // BATCH*NPTS
#define NS    64
#define KPTS  15
#define CKP   64
#define FDIM  256
#define HIDD  512
#define NHEAD 8
#define DHEAD 32
#define NLAY  2
#define R2    0.04f
#define KPE   0.08f
#define WIN   0.25f
#define EPSF  1e-5f
#define SCALE 0.17677669529663687f   // 1/sqrt(32)
#define CPITCH 264                   // 256 + 8 pad (bank-safe)

typedef __attribute__((ext_vector_type(8))) short          short8;
typedef __attribute__((ext_vector_type(8))) unsigned short ushort8;
typedef __attribute__((ext_vector_type(4))) float          f32x4;

static __device__ __forceinline__ unsigned short f2bf(float f) {
    unsigned int u = __float_as_uint(f);
    unsigned int r = u + 0x7fffu + ((u >> 16) & 1u);   // RNE
    return (unsigned short)(r >> 16);
}
static __device__ __forceinline__ float b2f(unsigned short u) {
    return __uint_as_float(((unsigned int)u) << 16);
}

// ------------- fused ball query + KPConv, batch staged in LDS -------------
// 256 blocks, 256 threads; block handles 32 points (4 waves x 8 each).
__global__ __launch_bounds__(256) void bkp_k(
    const float* __restrict__ pos, const float* __restrict__ feat,
    const float* __restrict__ kpts, const float* __restrict__ kpw,
    float* __restrict__ raw)
{
    __shared__ float xs[NPTS], ys[NPTS], zs[NPTS];
    __shared__ float f0s[NPTS], f1s[NPTS], f2s[NPTS];
    __shared__ float kpl[45];
    __shared__ float kpwl[45*CKP];
    __shared__ int   nb[4][64];
    __shared__ float wf[4][45];

    int tid = threadIdx.x;
    int w = tid >> 6, lane = tid & 63;
    int b = blockIdx.x >> 6;                 // 64 blocks per batch
    int base = b * NPTS;

    for (int t = tid; t < NPTS; t += 256) {
        const float* q = pos + (size_t)(base + t)*3;
        xs[t] = q[0]; ys[t] = q[1]; zs[t] = q[2];
        const float* f = feat + (size_t)(base + t)*3;
        f0s[t] = f[0]; f1s[t] = f[1]; f2s[t] = f[2];
    }
    if (tid < 45) kpl[tid] = kpts[tid];
    for (int t = tid; t < 45*CKP; t += 256) kpwl[t] = kpw[t];
    __syncthreads();

    int loc0 = (blockIdx.x & 63) * 32;       // first local point of this block

    for (int i = 0; i < 8; ++i) {
        int n_pt = loc0 + w*8 + i;
        float xi = xs[n_pt], yi = ys[n_pt], zi = zs[n_pt];

        // ---- ball query over LDS ----
        int count = 0;
        for (int jc = 0; jc < NPTS; jc += 64) {
            int j = jc + lane;
            float dx = xs[j] - xi;
            float dy = ys[j] - yi;
            float dz = zs[j] - zi;
            float d2 = dx*dx + dy*dy + dz*dz;
            bool within = d2 <= R2;
            unsigned long long m = __ballot(within);
            if (within) {
                int r = count + __popcll(m & ((1ull << lane) - 1ull));
                if (r < NS) nb[w][r] = j;
            }
            count += __popcll(m);
            if (count >= NS) break;          // wave-uniform
        }
        int cc = count < NS ? count : NS;
        if (lane >= cc) nb[w][lane] = -1;
        // per-wave LDS, wave-synchronous: no barrier needed

        // ---- KPConv for this point ----
        int id = nb[w][lane];
        bool val = id >= 0;
        float rx, ry, rz, g0, g1, g2;
        if (val) {
            rx = xs[id] - xi; ry = ys[id] - yi; rz = zs[id] - zi;
            g0 = f0s[id]; g1 = f1s[id]; g2 = f2s[id];
        } else {
            rx = 1e6f; ry = 1e6f; rz = 1e6f; g0 = g1 = g2 = 0.f;
        }
        #pragma unroll
        for (int k = 0; k < KPTS; ++k) {
            float dx = rx - kpl[k*3+0], dy = ry - kpl[k*3+1], dz = rz - kpl[k*3+2];
            float dist = sqrtf(dx*dx + dy*dy + dz*dz + 1e-12f);
            float infl = 1.0f - dist / KPE;
            infl = infl > 0.f ? infl : 0.f;
            float v0 = infl*g0, v1 = infl*g1, v2 = infl*g2;
            for (int off = 32; off; off >>= 1) {
                v0 += __shfl_down(v0, off);
                v1 += __shfl_down(v1, off);
                v2 += __shfl_down(v2, off);
            }
            if (lane == 0) { wf[w][k*3+0]=v0; wf[w][k*3+1]=v1; wf[w][k*3+2]=v2; }
        }
        float acc = 0.f;
        for (int t = 0; t < 45; ++t) acc += wf[w][t] * kpwl[t*CKP + lane];
        raw[(size_t)(base + n_pt)*CKP + lane] = acc;
    }
}

// ---------------- BN stats ----------------
__global__ void bn_stats_k(const float* __restrict__ raw, float* __restrict__ stats)
{
    int c = blockIdx.x, tid = threadIdx.x;
    float s = 0.f, q = 0.f;
    for (int p = tid; p < PTS; p += 256) { float v = raw[p*CKP + c]; s += v; q += v*v; }
    __shared__ float sh[256], sh2[256];
    sh[tid]=s; sh2[tid]=q; __syncthreads();
    for (int o = 128; o; o >>= 1) { if (tid < o) { sh[tid]+=sh[tid+o]; sh2[tid]+=sh2[tid+o]; } __syncthreads(); }
    if (tid == 0) { stats[c] = sh[0]; stats[CKP + c] = sh2[0]; }
}

// ------- cluster: per-batch min, cids, bitmask counting sort (deterministic) --
__global__ void cluster_k(const float* __restrict__ pos, int* __restrict__ sorted,
                          int* __restrict__ inv, int* __restrict__ offs,
                          int* __restrict__ hist)
{
    int b = blockIdx.x, tid = threadIdx.x;
    __shared__ float sx[256], sy[256], sz[256];
    float mx=1e30f, my=1e30f, mz=1e30f;
    for (int n = tid; n < NPTS; n += 256) {
        const float* q = pos + ((size_t)b*NPTS + n)*3;
        mx = fminf(mx, q[0]); my = fminf(my, q[1]); mz = fminf(mz, q[2]);
    }
    sx[tid]=mx; sy[tid]=my; sz[tid]=mz; __syncthreads();
    for (int o=128;o;o>>=1){ if(tid<o){sx[tid]=fminf(sx[tid],sx[tid+o]);sy[tid]=fminf(sy[tid],sy[tid+o]);sz[tid]=fminf(sz[tid],sz[tid+o]);} __syncthreads(); }
    float X = sx[0], Y = sy[0], Z = sz[0];

    __shared__ unsigned char cid_s[NPTS];
    __shared__ unsigned int  mask[64][64];   // [cluster][word-of-32-points]
    __shared__ int wpfx[64][64];
    __shared__ int tot[64], off_c[64];

    for (int i = tid; i < 64*64; i += 256) ((unsigned int*)mask)[i] = 0u;
    __syncthreads();

    for (int n = tid; n < NPTS; n += 256) {
        const float* q = pos + ((size_t)b*NPTS + n)*3;
        int cx = (int)floorf((q[0]-X)/WIN);
        int cy = (int)floorf((q[1]-Y)/WIN);
        int cz = (int)floorf((q[2]-Z)/WIN);
        int c = (cx<<4) | (cy<<2) | cz;
        cid_s[n] = (unsigned char)c;
        atomicOr(&mask[c][n>>5], 1u << (n & 31));
    }
    __syncthreads();

    if (tid < 64) {
        int run = 0;
        for (int wd = 0; wd < 64; ++wd) { wpfx[tid][wd] = run; run += __popc(mask[tid][wd]); }
        tot[tid] = run;
    }
    __syncthreads();
    if (tid == 0) { int run = 0; for (int c = 0; c < 64; ++c) { off_c[c] = run; run += tot[c]; } }
    __syncthreads();
    if (tid < 64) { hist[b*64+tid] = tot[tid]; offs[b*64+tid] = off_c[tid]; }

    for (int n = tid; n < NPTS; n += 256) {
        int c = cid_s[n];
        int wd = n >> 5;
        int rank = wpfx[c][wd] + __popc(mask[c][wd] & ((1u << (n & 31)) - 1u));
        int slot = b*NPTS + off_c[c] + rank;
        int p = b*NPTS + n;
        sorted[slot] = p;
        inv[p] = slot;
    }
}

// ------- BN + LeakyReLU + [pos|kpf] @ Wm -> x written in SORTED order --------
__global__ void embed_k(const float* __restrict__ pos, const float* __restrict__ raw,
                        const float* __restrict__ stats, const float* __restrict__ gamma,
                        const float* __restrict__ beta, const float* __restrict__ Wm,
                        const int* __restrict__ inv,
                        float* __restrict__ xs, unsigned short* __restrict__ xsb)
{
    int p = blockIdx.x, tid = threadIdx.x;
    __shared__ float pw[67];
    if (tid < 3) pw[tid] = pos[p*3 + tid];
    else if (tid < 67) {
        int c = tid - 3;
        float mu  = stats[c] * (1.0f/PTS);
        float var = stats[CKP+c] * (1.0f/PTS) - mu*mu;
        float v = raw[p*CKP + c];
        float h = gamma[c] * (v - mu) * rsqrtf(var + EPSF) + beta[c];
        pw[tid] = h >= 0.f ? h : 0.2f * h;
    }
    __syncthreads();
    float acc = 0.f;
    for (int c = 0; c < 67; ++c) acc += pw[c] * Wm[c*FDIM + tid];
    int slot = inv[p];
    xs[(size_t)slot*FDIM + tid] = acc;
    xsb[(size_t)slot*FDIM + tid] = f2bf(acc);
}

// ---------------- weight convert+transpose: [K][N] f32 -> [N][K] bf16 --------
__global__ void wconv_k(const float* __restrict__ Wq, const float* __restrict__ Wk,
                        const float* __restrict__ Wv, const float* __restrict__ Wo,
                        const float* __restrict__ W1, const float* __restrict__ W2,
                        unsigned short* __restrict__ wT)
{
    int id = blockIdx.z; int t = id >> 1, l = id & 1;
    const float* src; unsigned short* dst; int K, N;
    switch (t) {
        case 0: src=Wq+(size_t)l*65536;  dst=wT+(size_t)l*196608;             K=256; N=256; break;
        case 1: src=Wk+(size_t)l*65536;  dst=wT+(size_t)l*196608+65536;       K=256; N=256; break;
        case 2: src=Wv+(size_t)l*65536;  dst=wT+(size_t)l*196608+131072;      K=256; N=256; break;
        case 3: src=Wo+(size_t)l*65536;  dst=wT+393216+(size_t)l*65536;       K=256; N=256; break;
        case 4: src=W1+(size_t)l*131072; dst=wT+524288+(size_t)l*131072;      K=256; N=512; break;
        default:src=W2+(size_t)l*131072; dst=wT+786432+(size_t)l*131072;      K=512; N=256; break;
    }
    int n0 = blockIdx.x*32, k0 = blockIdx.y*32;
    if (n0 >= N || k0 >= K) return;
    __shared__ float ld[32][33];
    int tid = threadIdx.x;
    #pragma unroll
    for (int i = 0; i < 4; ++i) { int v=tid+i*256; int ty=v>>5, tx=v&31;
        ld[ty][tx] = src[(size_t)(k0+ty)*N + n0+tx]; }
    __syncthreads();
    #pragma unroll
    for (int i = 0; i < 4; ++i) { int v=tid+i*256; int ny=v>>5, nk=v&31;
        dst[(size_t)(n0+ny)*K + k0+nk] = f2bf(ld[nk][ny]); }
}

__global__ void packb_k(const float* __restrict__ bq, const float* __restrict__ bk,
                        const float* __restrict__ bv, float* __restrict__ bqkv)
{
    int l = blockIdx.x, n = threadIdx.x;   // 768 threads
    float v = (n < 256) ? bq[l*256+n] : (n < 512) ? bk[l*256+n-256] : bv[l*256+n-512];
    bqkv[l*768 + n] = v;
}

// ------ wide-tile bf16 MFMA GEMM, 32x256 tile, optional fused LayerNorm ------
// LNM: 0 none, 1 LN (Cf fp32 + Cb bf16), 2 LN final (scatter fp32 via sorted).
template<int ACT, int LNM>
__global__ __launch_bounds__(256) void bgemm256_k(
    const unsigned short* __restrict__ A, const unsigned short* __restrict__ Wt,
    const float* __restrict__ bias, const float* __restrict__ R,
    const float* __restrict__ g, const float* __restrict__ be,
    const int* __restrict__ sorted,
    float* __restrict__ Cf, unsigned short* __restrict__ Cb,
    int Nc, int K)
{
    __shared__ unsigned short As[32*72];
    __shared__ unsigned short Bs[256*72];
    __shared__ float red_s[4][32], red_q[4][32];
    int tid = threadIdx.x;
    int l = tid & 63, wc = tid >> 6;
    int lr = l & 15, lk = l >> 4;
    int bm = blockIdx.y * 32, bn = blockIdx.x * 256;

    f32x4 acc[2][4] = {};

    for (int k0 = 0; k0 < K; k0 += 64) {
        __syncthreads();
        {
            int row = tid >> 3, seg = tid & 7;
            *(ushort8*)&As[row*72 + seg*8] =
                *(const ushort8*)&A[(size_t)(bm + row)*K + k0 + seg*8];
        }
        #pragma unroll
        for (int i = 0; i < 8; ++i) {
            int id = tid + i*256;
            int row = id >> 3, seg = id & 7;
            *(ushort8*)&Bs[row*72 + seg*8] =
                *(const ushort8*)&Wt[(size_t)(bn + row)*K + k0 + seg*8];
        }
        __syncthreads();
        #pragma unroll
        for (int kk = 0; kk < 64; kk += 32) {
            short8 a[2], b[4];
            #pragma unroll
            for (int mi = 0; mi < 2; ++mi)
                a[mi] = *(const short8*)&As[(mi*16 + lr)*72 + kk + lk*8];
            #pragma unroll
            for (int ni = 0; ni < 4; ++ni)
                b[ni] = *(const short8*)&Bs[(wc*64 + ni*16 + lr)*72 + kk + lk*8];
            #pragma unroll
            for (int mi = 0; mi < 2; ++mi)
                #pragma unroll
                for (int ni = 0; ni < 4; ++ni)
                    acc[mi][ni] = __builtin_amdgcn_mfma_f32_16x16x32_bf16(
                        a[mi], b[ni], acc[mi][ni], 0, 0, 0);
        }
    }

    #pragma unroll
    for (int mi = 0; mi < 2; ++mi) {
        #pragma unroll
        for (int r = 0; r < 4; ++r) {
            int row = bm + mi*16 + lk*4 + r;
            #pragma unroll
            for (int ni = 0; ni < 4; ++ni) {
                int col = bn + wc*64 + ni*16 + lr;
                float v = acc[mi][ni][r] + bias[col];
                if (R) v += R[(size_t)row*Nc + col];
                if (ACT == 1) v = v > 0.f ? v : 0.f;
                acc[mi][ni][r] = v;
            }
        }
    }

    if (LNM == 0) {
        #pragma unroll
        for (int mi = 0; mi < 2; ++mi)
            #pragma unroll
            for (int r = 0; r < 4; ++r) {
                int row = bm + mi*16 + lk*4 + r;
                #pragma unroll
                for (int ni = 0; ni < 4; ++ni) {
                    int col = bn + wc*64 + ni*16 + lr;
                    if (Cf) Cf[(size_t)row*Nc + col] = acc[mi][ni][r];
                    if (Cb) Cb[(size_t)row*Nc + col] = f2bf(acc[mi][ni][r]);
                }
            }
    } else {
        #pragma unroll
        for (int mi = 0; mi < 2; ++mi) {
            #pragma unroll
            for (int r = 0; r < 4; ++r) {
                float ps = 0.f, pq = 0.f;
                #pragma unroll
                for (int ni = 0; ni < 4; ++ni) { float v = acc[mi][ni][r]; ps += v; pq += v*v; }
                ps += __shfl_xor(ps, 1);  pq += __shfl_xor(pq, 1);
                ps += __shfl_xor(ps, 2);  pq += __shfl_xor(pq, 2);
                ps += __shfl_xor(ps, 4);  pq += __shfl_xor(pq, 4);
                ps += __shfl_xor(ps, 8);  pq += __shfl_xor(pq, 8);
                if (lr == 0) {
                    int rl = mi*16 + lk*4 + r;
                    red_s[wc][rl] = ps;
                    red_q[wc][rl] = pq;
                }
            }
        }
        __syncthreads();
        #pragma unroll
        for (int mi = 0; mi < 2; ++mi) {
            #pragma unroll
            for (int r = 0; r < 4; ++r) {
                int rl = mi*16 + lk*4 + r;
                float s = red_s[0][rl] + red_s[1][rl] + red_s[2][rl] + red_s[3][rl];
                float q = red_q[0][rl] + red_q[1][rl] + red_q[2][rl] + red_q[3][rl];
                float mu  = s * (1.0f/FDIM);
                float var = q * (1.0f/FDIM) - mu*mu;
                float rs  = rsqrtf(var + EPSF);
                int row = bm + rl;
                #pragma unroll
                for (int ni = 0; ni < 4; ++ni) {
                    int col = wc*64 + ni*16 + lr;
                    float o = g[col]*(acc[mi][ni][r]-mu)*rs + be[col];
                    if (LNM == 2) Cf[(size_t)sorted[row]*FDIM + col] = o;
                    else          Cf[(size_t)row*FDIM + col] = o;
                    if (Cb) Cb[(size_t)row*FDIM + col] = f2bf(o);
                }
            }
        }
    }
}

// ---------------- cluster-local MFMA attention ----------------
__global__ __launch_bounds__(512) void attn_k(
    const unsigned short* __restrict__ qkv, const int* __restrict__ offs,
    const int* __restrict__ hist, unsigned short* __restrict__ o)
{
    int cci = blockIdx.x, b = blockIdx.y;
    int Mc = hist[b*64 + cci];
    if (Mc == 0) return;
    int off = b*NPTS + offs[b*64 + cci];
    __shared__ unsigned short Kl[64*CPITCH];
    __shared__ unsigned short Vl[64*CPITCH];
    __shared__ unsigned short Pl[8][64*72];
    int tid = threadIdx.x;

    if (Mc <= 64) {
        #pragma unroll
        for (int it = 0; it < 4; ++it) {
            int id = tid + it*512;
            int key = id >> 5, ch8 = (id & 31)*8;
            ushort8 kv, vv;
            if (key < Mc) {
                kv = *(const ushort8*)&qkv[(size_t)(off+key)*768 + 256 + ch8];
                vv = *(const ushort8*)&qkv[(size_t)(off+key)*768 + 512 + ch8];
            } else {
                kv = (ushort8)0; vv = (ushort8)0;
            }
            *(ushort8*)&Kl[key*CPITCH + ch8] = kv;
            *(ushort8*)&Vl[key*CPITCH + ch8] = vv;
        }
        __syncthreads();

        int w = tid >> 6, l = tid & 63;
        int h = w;
        int lr = l & 15, lk = l >> 4;

        f32x4 s[4][4] = {};
        short8 a[4], bb[4];
        #pragma unroll
        for (int mi = 0; mi < 4; ++mi) {
            int rg = off + mi*16 + lr;
            if (rg > PTS-1) rg = PTS-1;
            a[mi] = *(const short8*)&qkv[(size_t)rg*768 + h*32 + lk*8];
        }
        #pragma unroll
        for (int ni = 0; ni < 4; ++ni)
            bb[ni] = *(const short8*)&Kl[(ni*16+lr)*CPITCH + h*32 + lk*8];
        #pragma unroll
        for (int mi = 0; mi < 4; ++mi)
            #pragma unroll
            for (int ni = 0; ni < 4; ++ni)
                s[mi][ni] = __builtin_amdgcn_mfma_f32_16x16x32_bf16(a[mi], bb[ni], s[mi][ni], 0, 0, 0);

        unsigned short* Pw = Pl[w];
        float invl[4][4];
        #pragma unroll
        for (int mi = 0; mi < 4; ++mi) {
            #pragma unroll
            for (int r = 0; r < 4; ++r) {
                int row = mi*16 + lk*4 + r;
                float sv[4]; float mx = -1e30f;
                #pragma unroll
                for (int ni = 0; ni < 4; ++ni) {
                    int col = ni*16 + lr;
                    float x = s[mi][ni][r] * SCALE;
                    sv[ni] = (col < Mc) ? x : -1e30f;
                    mx = fmaxf(mx, sv[ni]);
                }
                mx = fmaxf(mx, __shfl_xor(mx, 1));
                mx = fmaxf(mx, __shfl_xor(mx, 2));
                mx = fmaxf(mx, __shfl_xor(mx, 4));
                mx = fmaxf(mx, __shfl_xor(mx, 8));
                float ls = 0.f;
                #pragma unroll
                for (int ni = 0; ni < 4; ++ni) {
                    float e = __expf(sv[ni] - mx);
                    ls += e;
                    Pw[row*72 + ni*16 + lr] = f2bf(e);
                }
                ls += __shfl_xor(ls, 1);
                ls += __shfl_xor(ls, 2);
                ls += __shfl_xor(ls, 4);
                ls += __shfl_xor(ls, 8);
                invl[mi][r] = 1.0f / ls;
            }
        }

        f32x4 oacc[4][2] = {};
        #pragma unroll
        for (int ks = 0; ks < 2; ++ks) {
            short8 bv[2];
            #pragma unroll
            for (int db = 0; db < 2; ++db) {
                short8 t;
                #pragma unroll
                for (int e = 0; e < 8; ++e)
                    t[e] = (short)Vl[(ks*32 + lk*8 + e)*CPITCH + h*32 + db*16 + lr];
                bv[db] = t;
            }
            #pragma unroll
            for (int mi = 0; mi < 4; ++mi) {
                short8 pa = *(const short8*)&Pw[(mi*16+lr)*72 + ks*32 + lk*8];
                #pragma unroll
                for (int db = 0; db < 2; ++db)
                    oacc[mi][db] = __builtin_amdgcn_mfma_f32_16x16x32_bf16(pa, bv[db], oacc[mi][db], 0, 0, 0);
            }
        }

        #pragma unroll
        for (int mi = 0; mi < 4; ++mi)
            #pragma unroll
            for (int db = 0; db < 2; ++db)
                #pragma unroll
                for (int r = 0; r < 4; ++r) {
                    int row = mi*16 + lk*4 + r;
                    if (row < Mc)
                        o[(size_t)(off+row)*FDIM + h*32 + db*16 + lr] =
                            f2bf(oacc[mi][db][r] * invl[mi][r]);
                }
    } else {
        for (int task = tid; task < Mc*NHEAD; task += 512) {
            int row = task >> 3, h = task & 7;
            float qr[DHEAD];
            #pragma unroll
            for (int d = 0; d < DHEAD; ++d)
                qr[d] = b2f(qkv[(size_t)(off+row)*768 + h*32 + d]);
            float m = -3e38f, lsum = 0.f, acc[DHEAD];
            #pragma unroll
            for (int d = 0; d < DHEAD; ++d) acc[d] = 0.f;
            for (int j = 0; j < Mc; ++j) {
                float dot = 0.f;
                #pragma unroll
                for (int d = 0; d < DHEAD; ++d)
                    dot += qr[d] * b2f(qkv[(size_t)(off+j)*768 + 256 + h*32 + d]);
                float sc = dot * SCALE;
                float mn = fmaxf(m, sc);
                float aa = __expf(m - mn);
                float e  = __expf(sc - mn);
                lsum = lsum*aa + e;
                #pragma unroll
                for (int d = 0; d < DHEAD; ++d)
                    acc[d] = acc[d]*aa + e * b2f(qkv[(size_t)(off+j)*768 + 512 + h*32 + d]);
                m = mn;
            }
            float inv = 1.0f / lsum;
            #pragma unroll
            for (int d = 0; d < DHEAD; ++d)
                o[(size_t)(off+row)*FDIM + h*32 + d] = f2bf(acc[d]*inv);
        }
    }
}

extern "C" void kernel_launch(void* const* d_in, const int* in_sizes, int n_in,
                              void* d_out, int out_size, void* d_ws, size_t ws_size,
                              hipStream_t stream)
{
    (void)in_sizes; (void)n_in; (void)out_size; (void)ws_size;
    const float* pos  = (const float*)d_in[0];
    const float* feat = (const float*)d_in[1];
    const float* kpts = (const float*)d_in[2];
    const float* kpw  = (const float*)d_in[3];
    const float* bn_g = (const float*)d_in[4];
    const float* bn_b = (const float*)d_in[5];
    const float* Wm   = (const float*)d_in[6];
    const float* Wq   = (const float*)d_in[7];
    const float* bq   = (const float*)d_in[8];
    const float* Wk   = (const float*)d_in[9];
    const float* bk   = (const float*)d_in[10];
    const float* Wv   = (const float*)d_in[11];
    const float* bv   = (const float*)d_in[12];
    const float* Wo   = (const float*)d_in[13];
    const float* bo   = (const float*)d_in[14];
    const float* g1   = (const float*)d_in[15];
    const float* be1  = (const float*)d_in[16];
    const float* W1   = (const float*)d_in[17];
    const float* bb1  = (const float*)d_in[18];
    const float* W2   = (const float*)d_in[19];
    const float* bb2  = (const float*)d_in[20];
    const float* g2   = (const float*)d_in[21];
    const float* be2  = (const float*)d_in[22];

    char* ws = (char*)d_ws;
    const size_t MB = 1024*1024;
    float* raw    = (float*)(ws + 0);                    // 2 MB
    float* stats  = (float*)(ws + 2*MB);                 // 512 B
    int*   hist   = (int*)(ws + 2*MB + 4096);            // 1 KB
    int*   offs   = hist + 256;
    int*   sorted = (int*)(ws + 2*MB + 16384);           // 32 KB
    int*   inv    = sorted + PTS;                        // 32 KB
    float* xs   = (float*)(ws + 5*MB);                   // [P,256] f32 (8 MB)
    float* x2   = (float*)(ws + 13*MB);                  // [P,256] f32 (8 MB)
    unsigned short* xsb   = (unsigned short*)(ws + 21*MB);  // [P,256] bf16 (4 MB)
    unsigned short* x2b   = (unsigned short*)(ws + 25*MB);  // [P,256] bf16 (4 MB)
    unsigned short* qkvb  = (unsigned short*)(ws + 29*MB);  // [P,768] bf16 (12 MB)
    unsigned short* attnb = (unsigned short*)(ws + 41*MB);  // [P,256] bf16 (4 MB)
    unsigned short* wT    = (unsigned short*)(ws + 45*MB);  // 2 MB
    float*          bqkv  = (float*)(ws + 47*MB);           // 6 KB
    unsigned short* hb    = qkvb;                            // [P,512] aliases qkv (dead)

    wconv_k<<<dim3(16,16,12), 256, 0, stream>>>(Wq, Wk, Wv, Wo, W1, W2, wT);
    packb_k<<<NLAY, 768, 0, stream>>>(bq, bk, bv, bqkv);
    cluster_k<<<BATCH, 256, 0, stream>>>(pos, sorted, inv, offs, hist);
    bkp_k<<<PTS/32, 256, 0, stream>>>(pos, feat, kpts, kpw, raw);
    bn_stats_k<<<CKP, 256, 0, stream>>>(raw, stats);
    embed_k<<<PTS, 256, 0, stream>>>(pos, raw, stats, bn_g, bn_b, Wm, inv, xs, xsb);

    for (int l = 0; l < NLAY; ++l) {
        bgemm256_k<0,0><<<dim3(3, PTS/32), 256, 0, stream>>>(
            xsb, wT + (size_t)l*196608, bqkv + l*768, nullptr, nullptr, nullptr, nullptr,
            nullptr, qkvb, 768, FDIM);
        attn_k<<<dim3(64, BATCH), 512, 0, stream>>>(qkvb, offs, hist, attnb);
        bgemm256_k<0,1><<<dim3(1, PTS/32), 256, 0, stream>>>(
            attnb, wT + 393216 + (size_t)l*65536, bo + l*FDIM, xs,
            g1 + l*FDIM, be1 + l*FDIM, nullptr, x2, x2b, FDIM, FDIM);
        bgemm256_k<1,0><<<dim3(2, PTS/32), 256, 0, stream>>>(
            x2b, wT + 524288 + (size_t)l*131072, bb1 + l*HIDD, nullptr, nullptr, nullptr,
            nullptr, nullptr, hb, HIDD, FDIM);
        if (l == NLAY-1)
            bgemm256_k<0,2><<<dim3(1, PTS/32), 256, 0, stream>>>(
                hb, wT + 786432 + (size_t)l*131072, bb2 + l*FDIM, x2,
                g2 + l*FDIM, be2 + l*FDIM, sorted, (float*)d_out, nullptr, FDIM, HIDD);
        else
            bgemm256_k<0,1><<<dim3(1, PTS/32), 256, 0, stream>>>(
                hb, wT + 786432 + (size_t)l*131072, bb2 + l*FDIM, x2,
                g2 + l*FDIM, be2 + l*FDIM, nullptr, xs, xsb, FDIM, HIDD);
    }
}

// Round 7
// 259.496 us; speedup vs baseline: 1.0828x; 1.0828x over previous
//
#include <hip/hip_runtime.h>
#include <math.h>

#define BATCH 4
#define NPTS  2048
#define PTS   8192      // BATCH*NPTS
#define NS    64
#define KPTS  15
#define CKP   64
#define FDIM  256
#define HIDD  512
#define NHEAD 8
#define DHEAD 32
#define NLAY  2
#define R2    0.04f
#define KPE   0.08f
#define WIN   0.25f
#define EPSF  1e-5f
#define SCALE 0.17677669529663687f   // 1/sqrt(32)
#define CPITCH 264                   // 256 + 8 pad (bank-safe)

typedef __attribute__((ext_vector_type(8))) short          short8;
typedef __attribute__((ext_vector_type(8))) unsigned short ushort8;
typedef __attribute__((ext_vector_type(4))) float          f32x4;

static __device__ __forceinline__ unsigned short f2bf(float f) {
    unsigned int u = __float_as_uint(f);
    unsigned int r = u + 0x7fffu + ((u >> 16) & 1u);   // RNE
    return (unsigned short)(r >> 16);
}
static __device__ __forceinline__ float b2f(unsigned short u) {
    return __uint_as_float(((unsigned int)u) << 16);
}

// ---- ball-query pass 1: per (query, chunk-of-64) in-radius bitmask ----------
// grid (32, BATCH, 4): candidate xyz in registers, queries broadcast from LDS.
__global__ __launch_bounds__(256) void mask_k(const float* __restrict__ pos,
                                              unsigned long long* __restrict__ masks)
{
    int chunk = blockIdx.x, b = blockIdx.y, qg = blockIdx.z;
    int tid = threadIdx.x, w = tid >> 6, lane = tid & 63;
    __shared__ float qx[512], qy[512], qz[512];
    int qbase = qg * 512;
    for (int t = tid; t < 512; t += 256) {
        const float* q = pos + (size_t)(b*NPTS + qbase + t)*3;
        qx[t] = q[0]; qy[t] = q[1]; qz[t] = q[2];
    }
    const float* c = pos + (size_t)(b*NPTS + chunk*64 + lane)*3;
    float cx = c[0], cy = c[1], cz = c[2];
    __syncthreads();
    int q0 = w * 128;
    for (int i = 0; i < 128; ++i) {
        int qi = q0 + i;
        float dx = cx - qx[qi], dy = cy - qy[qi], dz = cz - qz[qi];
        float d2 = dx*dx + dy*dy + dz*dz;
        unsigned long long m = __ballot(d2 <= R2);
        if (lane == 0) masks[(size_t)(b*NPTS + qbase + qi)*32 + chunk] = m;
    }
}

// ---- ball-query pass 2 + KPConv: one wave per point, shfl-broadcast select --
__global__ __launch_bounds__(512) void bkp3_k(
    const float* __restrict__ pos, const float* __restrict__ feat,
    const unsigned long long* __restrict__ masks,
    const float* __restrict__ kpts, const float* __restrict__ kpw,
    float* __restrict__ raw)
{
    __shared__ float kpwl[45*CKP];          // 11.25 KB
    __shared__ float kpl[45];
    __shared__ float wf[8][45];
    int tid = threadIdx.x, w = tid >> 6, lane = tid & 63;
    for (int t = tid; t < 45*CKP; t += 512) kpwl[t] = kpw[t];
    if (tid < 45) kpl[tid] = kpts[tid];
    int p = blockIdx.x*8 + w;
    int b = p >> 11;
    int base = b * NPTS;
    __syncthreads();

    // lane s finds the s-th in-radius neighbor (ascending index), register-only
    unsigned long long m = (lane < 32) ? masks[(size_t)p*32 + lane] : 0ull;
    int id = -1, run = 0;
    for (int wd = 0; wd < 32; ++wd) {
        unsigned long long wm = __shfl(m, wd);   // broadcast word wd (uniform)
        int c = __popcll(wm);
        if (id < 0 && lane >= run && lane < run + c) {
            int need = lane - run;
            unsigned long long mm = wm;
            for (int t = 0; t < need; ++t) mm &= mm - 1;
            id = wd*64 + __ffsll((long long)mm) - 1;
        }
        run += c;
        if (run >= NS) break;                    // uniform across wave
    }

    float xi = pos[(size_t)p*3+0], yi = pos[(size_t)p*3+1], zi = pos[(size_t)p*3+2];
    bool val = id >= 0;
    float rx, ry, rz, g0, g1, g2;
    if (val) {
        const float* pp = pos + (size_t)(base + id)*3;
        rx = pp[0]-xi; ry = pp[1]-yi; rz = pp[2]-zi;
        const float* ff = feat + (size_t)(base + id)*3;
        g0 = ff[0]; g1 = ff[1]; g2 = ff[2];
    } else {
        rx = 1e6f; ry = 1e6f; rz = 1e6f; g0 = g1 = g2 = 0.f;
    }
    #pragma unroll
    for (int k = 0; k < KPTS; ++k) {
        float dx = rx - kpl[k*3+0], dy = ry - kpl[k*3+1], dz = rz - kpl[k*3+2];
        float dist = sqrtf(dx*dx + dy*dy + dz*dz + 1e-12f);
        float infl = 1.0f - dist / KPE;
        infl = infl > 0.f ? infl : 0.f;
        float v0 = infl*g0, v1 = infl*g1, v2 = infl*g2;
        for (int off = 32; off; off >>= 1) {
            v0 += __shfl_down(v0, off);
            v1 += __shfl_down(v1, off);
            v2 += __shfl_down(v2, off);
        }
        if (lane == 0) { wf[w][k*3+0]=v0; wf[w][k*3+1]=v1; wf[w][k*3+2]=v2; }
    }
    float acc = 0.f;
    for (int t = 0; t < 45; ++t) acc += wf[w][t] * kpwl[t*CKP + lane];
    raw[(size_t)p*CKP + lane] = acc;
}

// ---------------- BN stats ----------------
__global__ void bn_stats_k(const float* __restrict__ raw, float* __restrict__ stats)
{
    int c = blockIdx.x, tid = threadIdx.x;
    float s = 0.f, q = 0.f;
    for (int p = tid; p < PTS; p += 256) { float v = raw[p*CKP + c]; s += v; q += v*v; }
    __shared__ float sh[256], sh2[256];
    sh[tid]=s; sh2[tid]=q; __syncthreads();
    for (int o = 128; o; o >>= 1) { if (tid < o) { sh[tid]+=sh[tid+o]; sh2[tid]+=sh2[tid+o]; } __syncthreads(); }
    if (tid == 0) { stats[c] = sh[0]; stats[CKP + c] = sh2[0]; }
}

// ------- cluster: per-batch min, cids, bitmask counting sort (deterministic) --
__global__ void cluster_k(const float* __restrict__ pos, int* __restrict__ sorted,
                          int* __restrict__ inv, int* __restrict__ offs,
                          int* __restrict__ hist)
{
    int b = blockIdx.x, tid = threadIdx.x;
    __shared__ float sx[256], sy[256], sz[256];
    float mx=1e30f, my=1e30f, mz=1e30f;
    for (int n = tid; n < NPTS; n += 256) {
        const float* q = pos + ((size_t)b*NPTS + n)*3;
        mx = fminf(mx, q[0]); my = fminf(my, q[1]); mz = fminf(mz, q[2]);
    }
    sx[tid]=mx; sy[tid]=my; sz[tid]=mz; __syncthreads();
    for (int o=128;o;o>>=1){ if(tid<o){sx[tid]=fminf(sx[tid],sx[tid+o]);sy[tid]=fminf(sy[tid],sy[tid+o]);sz[tid]=fminf(sz[tid],sz[tid+o]);} __syncthreads(); }
    float X = sx[0], Y = sy[0], Z = sz[0];

    __shared__ unsigned char cid_s[NPTS];
    __shared__ unsigned int  mask[64][64];
    __shared__ int wpfx[64][64];
    __shared__ int tot[64], off_c[64];

    for (int i = tid; i < 64*64; i += 256) ((unsigned int*)mask)[i] = 0u;
    __syncthreads();

    for (int n = tid; n < NPTS; n += 256) {
        const float* q = pos + ((size_t)b*NPTS + n)*3;
        int cx = (int)floorf((q[0]-X)/WIN);
        int cy = (int)floorf((q[1]-Y)/WIN);
        int cz = (int)floorf((q[2]-Z)/WIN);
        int c = (cx<<4) | (cy<<2) | cz;
        cid_s[n] = (unsigned char)c;
        atomicOr(&mask[c][n>>5], 1u << (n & 31));
    }
    __syncthreads();

    if (tid < 64) {
        int run = 0;
        for (int wd = 0; wd < 64; ++wd) { wpfx[tid][wd] = run; run += __popc(mask[tid][wd]); }
        tot[tid] = run;
    }
    __syncthreads();
    if (tid == 0) { int run = 0; for (int c = 0; c < 64; ++c) { off_c[c] = run; run += tot[c]; } }
    __syncthreads();
    if (tid < 64) { hist[b*64+tid] = tot[tid]; offs[b*64+tid] = off_c[tid]; }

    for (int n = tid; n < NPTS; n += 256) {
        int c = cid_s[n];
        int wd = n >> 5;
        int rank = wpfx[c][wd] + __popc(mask[c][wd] & ((1u << (n & 31)) - 1u));
        int slot = b*NPTS + off_c[c] + rank;
        int p = b*NPTS + n;
        sorted[slot] = p;
        inv[p] = slot;
    }
}

// ------- BN + LeakyReLU + [pos|kpf] @ Wm -> x written in SORTED order --------
__global__ void embed_k(const float* __restrict__ pos, const float* __restrict__ raw,
                        const float* __restrict__ stats, const float* __restrict__ gamma,
                        const float* __restrict__ beta, const float* __restrict__ Wm,
                        const int* __restrict__ inv,
                        float* __restrict__ xs, unsigned short* __restrict__ xsb)
{
    int p = blockIdx.x, tid = threadIdx.x;
    __shared__ float pw[67];
    if (tid < 3) pw[tid] = pos[p*3 + tid];
    else if (tid < 67) {
        int c = tid - 3;
        float mu  = stats[c] * (1.0f/PTS);
        float var = stats[CKP+c] * (1.0f/PTS) - mu*mu;
        float v = raw[p*CKP + c];
        float h = gamma[c] * (v - mu) * rsqrtf(var + EPSF) + beta[c];
        pw[tid] = h >= 0.f ? h : 0.2f * h;
    }
    __syncthreads();
    float acc = 0.f;
    for (int c = 0; c < 67; ++c) acc += pw[c] * Wm[c*FDIM + tid];
    int slot = inv[p];
    xs[(size_t)slot*FDIM + tid] = acc;
    xsb[(size_t)slot*FDIM + tid] = f2bf(acc);
}

// ---------------- weight convert+transpose: [K][N] f32 -> [N][K] bf16 --------
__global__ void wconv_k(const float* __restrict__ Wq, const float* __restrict__ Wk,
                        const float* __restrict__ Wv, const float* __restrict__ Wo,
                        const float* __restrict__ W1, const float* __restrict__ W2,
                        unsigned short* __restrict__ wT)
{
    int id = blockIdx.z; int t = id >> 1, l = id & 1;
    const float* src; unsigned short* dst; int K, N;
    switch (t) {
        case 0: src=Wq+(size_t)l*65536;  dst=wT+(size_t)l*196608;             K=256; N=256; break;
        case 1: src=Wk+(size_t)l*65536;  dst=wT+(size_t)l*196608+65536;       K=256; N=256; break;
        case 2: src=Wv+(size_t)l*65536;  dst=wT+(size_t)l*196608+131072;      K=256; N=256; break;
        case 3: src=Wo+(size_t)l*65536;  dst=wT+393216+(size_t)l*65536;       K=256; N=256; break;
        case 4: src=W1+(size_t)l*131072; dst=wT+524288+(size_t)l*131072;      K=256; N=512; break;
        default:src=W2+(size_t)l*131072; dst=wT+786432+(size_t)l*131072;      K=512; N=256; break;
    }
    int n0 = blockIdx.x*32, k0 = blockIdx.y*32;
    if (n0 >= N || k0 >= K) return;
    __shared__ float ld[32][33];
    int tid = threadIdx.x;
    #pragma unroll
    for (int i = 0; i < 4; ++i) { int v=tid+i*256; int ty=v>>5, tx=v&31;
        ld[ty][tx] = src[(size_t)(k0+ty)*N + n0+tx]; }
    __syncthreads();
    #pragma unroll
    for (int i = 0; i < 4; ++i) { int v=tid+i*256; int ny=v>>5, nk=v&31;
        dst[(size_t)(n0+ny)*K + k0+nk] = f2bf(ld[nk][ny]); }
}

__global__ void packb_k(const float* __restrict__ bq, const float* __restrict__ bk,
                        const float* __restrict__ bv, float* __restrict__ bqkv)
{
    int l = blockIdx.x, n = threadIdx.x;   // 768 threads
    float v = (n < 256) ? bq[l*256+n] : (n < 512) ? bk[l*256+n-256] : bv[l*256+n-512];
    bqkv[l*768 + n] = v;
}

// ------ wide-tile bf16 MFMA GEMM, 32x256 tile, optional fused LayerNorm ------
// LNM: 0 none, 1 LN (Cf fp32 + Cb bf16), 2 LN final (scatter fp32 via sorted).
template<int ACT, int LNM>
__global__ __launch_bounds__(256) void bgemm256_k(
    const unsigned short* __restrict__ A, const unsigned short* __restrict__ Wt,
    const float* __restrict__ bias, const float* __restrict__ R,
    const float* __restrict__ g, const float* __restrict__ be,
    const int* __restrict__ sorted,
    float* __restrict__ Cf, unsigned short* __restrict__ Cb,
    int Nc, int K)
{
    __shared__ unsigned short As[32*72];
    __shared__ unsigned short Bs[256*72];
    __shared__ float red_s[4][32], red_q[4][32];
    int tid = threadIdx.x;
    int l = tid & 63, wc = tid >> 6;
    int lr = l & 15, lk = l >> 4;
    int bm = blockIdx.y * 32, bn = blockIdx.x * 256;

    f32x4 acc[2][4] = {};

    for (int k0 = 0; k0 < K; k0 += 64) {
        __syncthreads();
        {
            int row = tid >> 3, seg = tid & 7;
            *(ushort8*)&As[row*72 + seg*8] =
                *(const ushort8*)&A[(size_t)(bm + row)*K + k0 + seg*8];
        }
        #pragma unroll
        for (int i = 0; i < 8; ++i) {
            int id = tid + i*256;
            int row = id >> 3, seg = id & 7;
            *(ushort8*)&Bs[row*72 + seg*8] =
                *(const ushort8*)&Wt[(size_t)(bn + row)*K + k0 + seg*8];
        }
        __syncthreads();
        #pragma unroll
        for (int kk = 0; kk < 64; kk += 32) {
            short8 a[2], b[4];
            #pragma unroll
            for (int mi = 0; mi < 2; ++mi)
                a[mi] = *(const short8*)&As[(mi*16 + lr)*72 + kk + lk*8];
            #pragma unroll
            for (int ni = 0; ni < 4; ++ni)
                b[ni] = *(const short8*)&Bs[(wc*64 + ni*16 + lr)*72 + kk + lk*8];
            #pragma unroll
            for (int mi = 0; mi < 2; ++mi)
                #pragma unroll
                for (int ni = 0; ni < 4; ++ni)
                    acc[mi][ni] = __builtin_amdgcn_mfma_f32_16x16x32_bf16(
                        a[mi], b[ni], acc[mi][ni], 0, 0, 0);
        }
    }

    #pragma unroll
    for (int mi = 0; mi < 2; ++mi) {
        #pragma unroll
        for (int r = 0; r < 4; ++r) {
            int row = bm + mi*16 + lk*4 + r;
            #pragma unroll
            for (int ni = 0; ni < 4; ++ni) {
                int col = bn + wc*64 + ni*16 + lr;
                float v = acc[mi][ni][r] + bias[col];
                if (R) v += R[(size_t)row*Nc + col];
                if (ACT == 1) v = v > 0.f ? v : 0.f;
                acc[mi][ni][r] = v;
            }
        }
    }

    if (LNM == 0) {
        #pragma unroll
        for (int mi = 0; mi < 2; ++mi)
            #pragma unroll
            for (int r = 0; r < 4; ++r) {
                int row = bm + mi*16 + lk*4 + r;
                #pragma unroll
                for (int ni = 0; ni < 4; ++ni) {
                    int col = bn + wc*64 + ni*16 + lr;
                    if (Cf) Cf[(size_t)row*Nc + col] = acc[mi][ni][r];
                    if (Cb) Cb[(size_t)row*Nc + col] = f2bf(acc[mi][ni][r]);
                }
            }
    } else {
        #pragma unroll
        for (int mi = 0; mi < 2; ++mi) {
            #pragma unroll
            for (int r = 0; r < 4; ++r) {
                float ps = 0.f, pq = 0.f;
                #pragma unroll
                for (int ni = 0; ni < 4; ++ni) { float v = acc[mi][ni][r]; ps += v; pq += v*v; }
                ps += __shfl_xor(ps, 1);  pq += __shfl_xor(pq, 1);
                ps += __shfl_xor(ps, 2);  pq += __shfl_xor(pq, 2);
                ps += __shfl_xor(ps, 4);  pq += __shfl_xor(pq, 4);
                ps += __shfl_xor(ps, 8);  pq += __shfl_xor(pq, 8);
                if (lr == 0) {
                    int rl = mi*16 + lk*4 + r;
                    red_s[wc][rl] = ps;
                    red_q[wc][rl] = pq;
                }
            }
        }
        __syncthreads();
        #pragma unroll
        for (int mi = 0; mi < 2; ++mi) {
            #pragma unroll
            for (int r = 0; r < 4; ++r) {
                int rl = mi*16 + lk*4 + r;
                float s = red_s[0][rl] + red_s[1][rl] + red_s[2][rl] + red_s[3][rl];
                float q = red_q[0][rl] + red_q[1][rl] + red_q[2][rl] + red_q[3][rl];
                float mu  = s * (1.0f/FDIM);
                float var = q * (1.0f/FDIM) - mu*mu;
                float rs  = rsqrtf(var + EPSF);
                int row = bm + rl;
                #pragma unroll
                for (int ni = 0; ni < 4; ++ni) {
                    int col = wc*64 + ni*16 + lr;
                    float o = g[col]*(acc[mi][ni][r]-mu)*rs + be[col];
                    if (LNM == 2) Cf[(size_t)sorted[row]*FDIM + col] = o;
                    else          Cf[(size_t)row*FDIM + col] = o;
                    if (Cb) Cb[(size_t)row*FDIM + col] = f2bf(o);
                }
            }
        }
    }
}

// ---------------- cluster-local MFMA attention ----------------
__global__ __launch_bounds__(512) void attn_k(
    const unsigned short* __restrict__ qkv, const int* __restrict__ offs,
    const int* __restrict__ hist, unsigned short* __restrict__ o)
{
    int cci = blockIdx.x, b = blockIdx.y;
    int Mc = hist[b*64 + cci];
    if (Mc == 0) return;
    int off = b*NPTS + offs[b*64 + cci];
    __shared__ unsigned short Kl[64*CPITCH];
    __shared__ unsigned short Vl[64*CPITCH];
    __shared__ unsigned short Pl[8][64*72];
    int tid = threadIdx.x;

    if (Mc <= 64) {
        #pragma unroll
        for (int it = 0; it < 4; ++it) {
            int id = tid + it*512;
            int key = id >> 5, ch8 = (id & 31)*8;
            ushort8 kv, vv;
            if (key < Mc) {
                kv = *(const ushort8*)&qkv[(size_t)(off+key)*768 + 256 + ch8];
                vv = *(const ushort8*)&qkv[(size_t)(off+key)*768 + 512 + ch8];
            } else {
                kv = (ushort8)0; vv = (ushort8)0;
            }
            *(ushort8*)&Kl[key*CPITCH + ch8] = kv;
            *(ushort8*)&Vl[key*CPITCH + ch8] = vv;
        }
        __syncthreads();

        int w = tid >> 6, l = tid & 63;
        int h = w;
        int lr = l & 15, lk = l >> 4;

        f32x4 s[4][4] = {};
        short8 a[4], bb[4];
        #pragma unroll
        for (int mi = 0; mi < 4; ++mi) {
            int rg = off + mi*16 + lr;
            if (rg > PTS-1) rg = PTS-1;
            a[mi] = *(const short8*)&qkv[(size_t)rg*768 + h*32 + lk*8];
        }
        #pragma unroll
        for (int ni = 0; ni < 4; ++ni)
            bb[ni] = *(const short8*)&Kl[(ni*16+lr)*CPITCH + h*32 + lk*8];
        #pragma unroll
        for (int mi = 0; mi < 4; ++mi)
            #pragma unroll
            for (int ni = 0; ni < 4; ++ni)
                s[mi][ni] = __builtin_amdgcn_mfma_f32_16x16x32_bf16(a[mi], bb[ni], s[mi][ni], 0, 0, 0);

        unsigned short* Pw = Pl[w];
        float invl[4][4];
        #pragma unroll
        for (int mi = 0; mi < 4; ++mi) {
            #pragma unroll
            for (int r = 0; r < 4; ++r) {
                int row = mi*16 + lk*4 + r;
                float sv[4]; float mx = -1e30f;
                #pragma unroll
                for (int ni = 0; ni < 4; ++ni) {
                    int col = ni*16 + lr;
                    float x = s[mi][ni][r] * SCALE;
                    sv[ni] = (col < Mc) ? x : -1e30f;
                    mx = fmaxf(mx, sv[ni]);
                }
                mx = fmaxf(mx, __shfl_xor(mx, 1));
                mx = fmaxf(mx, __shfl_xor(mx, 2));
                mx = fmaxf(mx, __shfl_xor(mx, 4));
                mx = fmaxf(mx, __shfl_xor(mx, 8));
                float ls = 0.f;
                #pragma unroll
                for (int ni = 0; ni < 4; ++ni) {
                    float e = __expf(sv[ni] - mx);
                    ls += e;
                    Pw[row*72 + ni*16 + lr] = f2bf(e);
                }
                ls += __shfl_xor(ls, 1);
                ls += __shfl_xor(ls, 2);
                ls += __shfl_xor(ls, 4);
                ls += __shfl_xor(ls, 8);
                invl[mi][r] = 1.0f / ls;
            }
        }

        f32x4 oacc[4][2] = {};
        #pragma unroll
        for (int ks = 0; ks < 2; ++ks) {
            short8 bv[2];
            #pragma unroll
            for (int db = 0; db < 2; ++db) {
                short8 t;
                #pragma unroll
                for (int e = 0; e < 8; ++e)
                    t[e] = (short)Vl[(ks*32 + lk*8 + e)*CPITCH + h*32 + db*16 + lr];
                bv[db] = t;
            }
            #pragma unroll
            for (int mi = 0; mi < 4; ++mi) {
                short8 pa = *(const short8*)&Pw[(mi*16+lr)*72 + ks*32 + lk*8];
                #pragma unroll
                for (int db = 0; db < 2; ++db)
                    oacc[mi][db] = __builtin_amdgcn_mfma_f32_16x16x32_bf16(pa, bv[db], oacc[mi][db], 0, 0, 0);
            }
        }

        #pragma unroll
        for (int mi = 0; mi < 4; ++mi)
            #pragma unroll
            for (int db = 0; db < 2; ++db)
                #pragma unroll
                for (int r = 0; r < 4; ++r) {
                    int row = mi*16 + lk*4 + r;
                    if (row < Mc)
                        o[(size_t)(off+row)*FDIM + h*32 + db*16 + lr] =
                            f2bf(oacc[mi][db][r] * invl[mi][r]);
                }
    } else {
        for (int task = tid; task < Mc*NHEAD; task += 512) {
            int row = task >> 3, h = task & 7;
            float qr[DHEAD];
            #pragma unroll
            for (int d = 0; d < DHEAD; ++d)
                qr[d] = b2f(qkv[(size_t)(off+row)*768 + h*32 + d]);
            float m = -3e38f, lsum = 0.f, acc[DHEAD];
            #pragma unroll
            for (int d = 0; d < DHEAD; ++d) acc[d] = 0.f;
            for (int j = 0; j < Mc; ++j) {
                float dot = 0.f;
                #pragma unroll
                for (int d = 0; d < DHEAD; ++d)
                    dot += qr[d] * b2f(qkv[(size_t)(off+j)*768 + 256 + h*32 + d]);
                float sc = dot * SCALE;
                float mn = fmaxf(m, sc);
                float aa = __expf(m - mn);
                float e  = __expf(sc - mn);
                lsum = lsum*aa + e;
                #pragma unroll
                for (int d = 0; d < DHEAD; ++d)
                    acc[d] = acc[d]*aa + e * b2f(qkv[(size_t)(off+j)*768 + 512 + h*32 + d]);
                m = mn;
            }
            float inv = 1.0f / lsum;
            #pragma unroll
            for (int d = 0; d < DHEAD; ++d)
                o[(size_t)(off+row)*FDIM + h*32 + d] = f2bf(acc[d]*inv);
        }
    }
}

extern "C" void kernel_launch(void* const* d_in, const int* in_sizes, int n_in,
                              void* d_out, int out_size, void* d_ws, size_t ws_size,
                              hipStream_t stream)
{
    (void)in_sizes; (void)n_in; (void)out_size; (void)ws_size;
    const float* pos  = (const float*)d_in[0];
    const float* feat = (const float*)d_in[1];
    const float* kpts = (const float*)d_in[2];
    const float* kpw  = (const float*)d_in[3];
    const float* bn_g = (const float*)d_in[4];
    const float* bn_b = (const float*)d_in[5];
    const float* Wm   = (const float*)d_in[6];
    const float* Wq   = (const float*)d_in[7];
    const float* bq   = (const float*)d_in[8];
    const float* Wk   = (const float*)d_in[9];
    const float* bk   = (const float*)d_in[10];
    const float* Wv   = (const float*)d_in[11];
    const float* bv   = (const float*)d_in[12];
    const float* Wo   = (const float*)d_in[13];
    const float* bo   = (const float*)d_in[14];
    const float* g1   = (const float*)d_in[15];
    const float* be1  = (const float*)d_in[16];
    const float* W1   = (const float*)d_in[17];
    const float* bb1  = (const float*)d_in[18];
    const float* W2   = (const float*)d_in[19];
    const float* bb2  = (const float*)d_in[20];
    const float* g2   = (const float*)d_in[21];
    const float* be2  = (const float*)d_in[22];

    char* ws = (char*)d_ws;
    const size_t MB = 1024*1024;
    float* raw    = (float*)(ws + 0);                    // 2 MB
    unsigned long long* masks = (unsigned long long*)(ws + 2*MB);  // 2 MB
    float* stats  = (float*)(ws + 4*MB);                 // 512 B
    int*   hist   = (int*)(ws + 4*MB + 4096);            // 1 KB
    int*   offs   = hist + 256;
    int*   sorted = (int*)(ws + 4*MB + 16384);           // 32 KB
    int*   inv    = sorted + PTS;                        // 32 KB
    float* xs   = (float*)(ws + 5*MB);                   // [P,256] f32 (8 MB)
    float* x2   = (float*)(ws + 13*MB);                  // [P,256] f32 (8 MB)
    unsigned short* xsb   = (unsigned short*)(ws + 21*MB);  // [P,256] bf16 (4 MB)
    unsigned short* x2b   = (unsigned short*)(ws + 25*MB);  // [P,256] bf16 (4 MB)
    unsigned short* qkvb  = (unsigned short*)(ws + 29*MB);  // [P,768] bf16 (12 MB)
    unsigned short* attnb = (unsigned short*)(ws + 41*MB);  // [P,256] bf16 (4 MB)
    unsigned short* wT    = (unsigned short*)(ws + 45*MB);  // 2 MB
    float*          bqkv  = (float*)(ws + 47*MB);           // 6 KB
    unsigned short* hb    = qkvb;                            // [P,512] aliases qkv (dead)

    wconv_k<<<dim3(16,16,12), 256, 0, stream>>>(Wq, Wk, Wv, Wo, W1, W2, wT);
    packb_k<<<NLAY, 768, 0, stream>>>(bq, bk, bv, bqkv);
    cluster_k<<<BATCH, 256, 0, stream>>>(pos, sorted, inv, offs, hist);
    mask_k<<<dim3(32, BATCH, 4), 256, 0, stream>>>(pos, masks);
    bkp3_k<<<PTS/8, 512, 0, stream>>>(pos, feat, masks, kpts, kpw, raw);
    bn_stats_k<<<CKP, 256, 0, stream>>>(raw, stats);
    embed_k<<<PTS, 256, 0, stream>>>(pos, raw, stats, bn_g, bn_b, Wm, inv, xs, xsb);

    for (int l = 0; l < NLAY; ++l) {
        bgemm256_k<0,0><<<dim3(3, PTS/32), 256, 0, stream>>>(
            xsb, wT + (size_t)l*196608, bqkv + l*768, nullptr, nullptr, nullptr, nullptr,
            nullptr, qkvb, 768, FDIM);
        attn_k<<<dim3(64, BATCH), 512, 0, stream>>>(qkvb, offs, hist, attnb);
        bgemm256_k<0,1><<<dim3(1, PTS/32), 256, 0, stream>>>(
            attnb, wT + 393216 + (size_t)l*65536, bo + l*FDIM, xs,
            g1 + l*FDIM, be1 + l*FDIM, nullptr, x2, x2b, FDIM, FDIM);
        bgemm256_k<1,0><<<dim3(2, PTS/32), 256, 0, stream>>>(
            x2b, wT + 524288 + (size_t)l*131072, bb1 + l*HIDD, nullptr, nullptr, nullptr,
            nullptr, nullptr, hb, HIDD, FDIM);
        if (l == NLAY-1)
            bgemm256_k<0,2><<<dim3(1, PTS/32), 256, 0, stream>>>(
                hb, wT + 786432 + (size_t)l*131072, bb2 + l*FDIM, x2,
                g2 + l*FDIM, be2 + l*FDIM, sorted, (float*)d_out, nullptr, FDIM, HIDD);
        else
            bgemm256_k<0,1><<<dim3(1, PTS/32), 256, 0, stream>>>(
                hb, wT + 786432 + (size_t)l*131072, bb2 + l*FDIM, x2,
                g2 + l*FDIM, be2 + l*FDIM, nullptr, xs, xsb, FDIM, HIDD);
    }
}

// Round 8
// 239.146 us; speedup vs baseline: 1.1749x; 1.0851x over previous
//
#include <hip/hip_runtime.h>
#include <math.h>

#define BATCH 4
#define NPTS  2048
#define PTS   8192      // BATCH*NPTS
#define NS    64
#define KPTS  15
#define CKP   64
#define FDIM  256
#define HIDD  512
#define NHEAD 8
#define DHEAD 32
#define NLAY  2
#define R2    0.04f
#define KPE   0.08f
#define WIN   0.25f
#define EPSF  1e-5f
#define SCALE 0.17677669529663687f   // 1/sqrt(32)
#define CPITCH 264                   // 256 + 8 pad (bank-safe)

typedef __attribute__((ext_vector_type(8))) short          short8;
typedef __attribute__((ext_vector_type(8))) unsigned short ushort8;
typedef __attribute__((ext_vector_type(4))) float          f32x4;

static __device__ __forceinline__ unsigned short f2bf(float f) {
    unsigned int u = __float_as_uint(f);
    unsigned int r = u + 0x7fffu + ((u >> 16) & 1u);   // RNE
    return (unsigned short)(r >> 16);
}
static __device__ __forceinline__ float b2f(unsigned short u) {
    return __uint_as_float(((unsigned int)u) << 16);
}

// ================= fused prep: wconv + packb + cluster + mask =================
// blocks: [0,3072) wconv | [3072,3584) mask | [3584,3588) cluster | [3588,3594) packb
__global__ __launch_bounds__(256) void prep_k(
    const float* __restrict__ pos,
    const float* __restrict__ Wq, const float* __restrict__ Wk,
    const float* __restrict__ Wv, const float* __restrict__ Wo,
    const float* __restrict__ W1, const float* __restrict__ W2,
    const float* __restrict__ bq, const float* __restrict__ bk,
    const float* __restrict__ bv,
    unsigned short* __restrict__ wT, float* __restrict__ bqkv,
    int* __restrict__ sorted, int* __restrict__ inv,
    int* __restrict__ offs, int* __restrict__ hist,
    unsigned long long* __restrict__ masks)
{
    __shared__ __align__(16) unsigned char sm[38400];
    int bid = blockIdx.x, tid = threadIdx.x;

    if (bid < 3072) {
        // ---------------- wconv: [K][N] f32 -> [N][K] bf16 ----------------
        int z = bid >> 8, r = bid & 255;
        int bx = r & 15, by = r >> 4;
        int t = z >> 1, l = z & 1;
        const float* src; unsigned short* dst; int K, N;
        switch (t) {
            case 0: src=Wq+(size_t)l*65536;  dst=wT+(size_t)l*196608;           K=256; N=256; break;
            case 1: src=Wk+(size_t)l*65536;  dst=wT+(size_t)l*196608+65536;     K=256; N=256; break;
            case 2: src=Wv+(size_t)l*65536;  dst=wT+(size_t)l*196608+131072;    K=256; N=256; break;
            case 3: src=Wo+(size_t)l*65536;  dst=wT+393216+(size_t)l*65536;     K=256; N=256; break;
            case 4: src=W1+(size_t)l*131072; dst=wT+524288+(size_t)l*131072;    K=256; N=512; break;
            default:src=W2+(size_t)l*131072; dst=wT+786432+(size_t)l*131072;    K=512; N=256; break;
        }
        int n0 = bx*32, k0 = by*32;
        if (n0 >= N || k0 >= K) return;
        float* ld = (float*)sm;   // [32][33]
        #pragma unroll
        for (int i = 0; i < 4; ++i) { int v=tid+i*256; int ty=v>>5, tx=v&31;
            ld[ty*33+tx] = src[(size_t)(k0+ty)*N + n0+tx]; }
        __syncthreads();
        #pragma unroll
        for (int i = 0; i < 4; ++i) { int v=tid+i*256; int ny=v>>5, nk=v&31;
            dst[(size_t)(n0+ny)*K + k0+nk] = f2bf(ld[nk*33+ny]); }
    } else if (bid < 3584) {
        // ---------------- mask: per (query, chunk-of-64) bitmask ----------------
        int m_ = bid - 3072;
        int chunk = m_ & 31, b = (m_ >> 5) & 3, qg = m_ >> 7;
        int w = tid >> 6, lane = tid & 63;
        float* qx = (float*)sm; float* qy = qx + 512; float* qz = qy + 512;
        int qbase = qg * 512;
        for (int t = tid; t < 512; t += 256) {
            const float* q = pos + (size_t)(b*NPTS + qbase + t)*3;
            qx[t] = q[0]; qy[t] = q[1]; qz[t] = q[2];
        }
        const float* c = pos + (size_t)(b*NPTS + chunk*64 + lane)*3;
        float cx = c[0], cy = c[1], cz = c[2];
        __syncthreads();
        int q0 = w * 128;
        for (int i = 0; i < 128; ++i) {
            int qi = q0 + i;
            float dx = cx - qx[qi], dy = cy - qy[qi], dz = cz - qz[qi];
            float d2 = dx*dx + dy*dy + dz*dz;
            unsigned long long m = __ballot(d2 <= R2);
            if (lane == 0) masks[(size_t)(b*NPTS + qbase + qi)*32 + chunk] = m;
        }
    } else if (bid < 3588) {
        // ---------------- cluster: min + cid + bitmask counting sort ----------------
        int b = bid - 3584;
        float* sx = (float*)sm; float* sy = sx + 256; float* sz = sy + 256;
        unsigned char* cid_s = sm + 3072;
        unsigned int* maskc = (unsigned int*)(sm + 5120);    // [64][64]
        int* wpfx = (int*)(sm + 21504);                      // [64][64]
        int* tot  = (int*)(sm + 37888);
        int* off_c= (int*)(sm + 38144);
        float mx=1e30f, my=1e30f, mz=1e30f;
        for (int n = tid; n < NPTS; n += 256) {
            const float* q = pos + ((size_t)b*NPTS + n)*3;
            mx = fminf(mx, q[0]); my = fminf(my, q[1]); mz = fminf(mz, q[2]);
        }
        sx[tid]=mx; sy[tid]=my; sz[tid]=mz; __syncthreads();
        for (int o=128;o;o>>=1){ if(tid<o){sx[tid]=fminf(sx[tid],sx[tid+o]);sy[tid]=fminf(sy[tid],sy[tid+o]);sz[tid]=fminf(sz[tid],sz[tid+o]);} __syncthreads(); }
        float X = sx[0], Y = sy[0], Z = sz[0];
        __syncthreads();
        for (int i = tid; i < 64*64; i += 256) maskc[i] = 0u;
        __syncthreads();
        for (int n = tid; n < NPTS; n += 256) {
            const float* q = pos + ((size_t)b*NPTS + n)*3;
            int cx = (int)floorf((q[0]-X)/WIN);
            int cy = (int)floorf((q[1]-Y)/WIN);
            int cz = (int)floorf((q[2]-Z)/WIN);
            int c = (cx<<4) | (cy<<2) | cz;
            cid_s[n] = (unsigned char)c;
            atomicOr(&maskc[c*64 + (n>>5)], 1u << (n & 31));
        }
        __syncthreads();
        if (tid < 64) {
            int run = 0;
            for (int wd = 0; wd < 64; ++wd) { wpfx[tid*64+wd] = run; run += __popc(maskc[tid*64+wd]); }
            tot[tid] = run;
        }
        __syncthreads();
        if (tid == 0) { int run = 0; for (int c = 0; c < 64; ++c) { off_c[c] = run; run += tot[c]; } }
        __syncthreads();
        if (tid < 64) { hist[b*64+tid] = tot[tid]; offs[b*64+tid] = off_c[tid]; }
        for (int n = tid; n < NPTS; n += 256) {
            int c = cid_s[n];
            int wd = n >> 5;
            int rank = wpfx[c*64+wd] + __popc(maskc[c*64+wd] & ((1u << (n & 31)) - 1u));
            int slot = b*NPTS + off_c[c] + rank;
            int p = b*NPTS + n;
            sorted[slot] = p;
            inv[p] = slot;
        }
    } else {
        // ---------------- packb ----------------
        int i = (bid - 3588)*256 + tid;
        if (i < 2*768) {
            int l = i / 768, n = i - l*768;
            float v = (n < 256) ? bq[l*256+n] : (n < 512) ? bk[l*256+n-256] : bv[l*256+n-512];
            bqkv[l*768 + n] = v;
        }
    }
}

// ======== KPConv: select (LDS) + lane-per-point register accumulate ==========
// 128 blocks x 256 threads; block = 64 points. Wave w covers neighbors [w*16,w*16+16).
__global__ __launch_bounds__(256) void kpc_k(
    const float* __restrict__ pos, const float* __restrict__ feat,
    const unsigned long long* __restrict__ masks,
    const float* __restrict__ kpts, const float* __restrict__ kpw,
    float* __restrict__ raw)
{
    __shared__ int   idxs[64][66];          // 16.9 KB (stride 66: 2-way max)
    __shared__ float kpwl[45*64];           // 11.5 KB
    __shared__ float kpl[48];
    __shared__ float wfp[64*181 + 4];       // 46.4 KB: [p]*181 + t*4 + wave

    int tid = threadIdx.x, w = tid >> 6, lane = tid & 63;
    int pb = blockIdx.x * 64;               // first global point of block
    int b = pb >> 11;
    int base = b * NPTS;

    for (int t = tid; t < 45*64; t += 256) kpwl[t] = kpw[t];
    if (tid < 45) kpl[tid] = kpts[tid];

    // ---- phase 0: neighbor select, 8 points at a time (32 threads/point) ----
    int g = tid >> 5, j = tid & 31;         // g: point-in-group, j: mask word
    for (int pp = 0; pp < 8; ++pp) {
        int lp = pp*8 + g;                  // local point
        unsigned long long m = masks[(size_t)(pb + lp)*32 + j];
        int cnt = __popcll(m);
        int inc = cnt;
        #pragma unroll
        for (int off = 1; off < 32; off <<= 1) {
            int v = __shfl_up(inc, off, 32);
            if (j >= off) inc += v;
        }
        int pfx = inc - cnt;
        int total = __shfl(inc, 31, 32);
        unsigned long long mm = m; int slot = pfx;
        while (mm && slot < NS) {
            int bit = __ffsll((long long)mm) - 1;
            idxs[lp][slot++] = j*64 + bit;   // local index in batch
            mm &= mm - 1;
        }
        int cc = total < NS ? total : NS;
        for (int s = cc + j; s < NS; s += 32) idxs[lp][s] = NPTS;
    }
    __syncthreads();

    // ---- phase A: accumulate wf[45] in registers, lane = local point ----
    float wf[45];
    #pragma unroll
    for (int t = 0; t < 45; ++t) wf[t] = 0.f;
    {
        int p = pb + lane;
        float xi = pos[(size_t)p*3+0], yi = pos[(size_t)p*3+1], zi = pos[(size_t)p*3+2];
        for (int n = w*16; n < w*16 + 16; ++n) {
            int id = idxs[lane][n];
            if (id < NPTS) {
                const float* pq = pos + (size_t)(base + id)*3;
                float rx = pq[0]-xi, ry = pq[1]-yi, rz = pq[2]-zi;
                const float* ff = feat + (size_t)(base + id)*3;
                float g0 = ff[0], g1 = ff[1], g2 = ff[2];
                #pragma unroll
                for (int k = 0; k < KPTS; ++k) {
                    float dx = rx - kpl[k*3+0], dy = ry - kpl[k*3+1], dz = rz - kpl[k*3+2];
                    float dist = sqrtf(dx*dx + dy*dy + dz*dz + 1e-12f);
                    float infl = fmaxf(0.f, 1.0f - dist * (1.0f/KPE));
                    wf[k*3+0] = fmaf(infl, g0, wf[k*3+0]);
                    wf[k*3+1] = fmaf(infl, g1, wf[k*3+1]);
                    wf[k*3+2] = fmaf(infl, g2, wf[k*3+2]);
                }
            }
        }
    }
    // ---- phase B: partials to LDS ----
    #pragma unroll
    for (int t = 0; t < 45; ++t) wfp[lane*181 + t*4 + w] = wf[t];
    __syncthreads();
    // ---- phase C1: sum 4 partials ----
    for (int i = tid; i < 64*45; i += 256) {
        int p_ = i / 45, t = i - p_*45;
        float* q = &wfp[p_*181 + t*4];
        q[0] = (q[0]+q[1]) + (q[2]+q[3]);
    }
    __syncthreads();
    // ---- phase C2: out[p][c] = sum_t wf[p][t]*kpw[t][c] ----
    {
        int c = tid & 63, pg = tid >> 6;
        float kw[45];
        #pragma unroll
        for (int t = 0; t < 45; ++t) kw[t] = kpwl[t*64 + c];
        for (int p0 = 0; p0 < 16; p0 += 4) {
            float a0=0.f, a1=0.f, a2=0.f, a3=0.f;
            int pl = pg*16 + p0;
            #pragma unroll
            for (int t = 0; t < 45; ++t) {
                a0 = fmaf(kw[t], wfp[(pl+0)*181 + t*4], a0);
                a1 = fmaf(kw[t], wfp[(pl+1)*181 + t*4], a1);
                a2 = fmaf(kw[t], wfp[(pl+2)*181 + t*4], a2);
                a3 = fmaf(kw[t], wfp[(pl+3)*181 + t*4], a3);
            }
            raw[(size_t)(pb + pl+0)*CKP + c] = a0;
            raw[(size_t)(pb + pl+1)*CKP + c] = a1;
            raw[(size_t)(pb + pl+2)*CKP + c] = a2;
            raw[(size_t)(pb + pl+3)*CKP + c] = a3;
        }
    }
}

// ---------------- BN stats ----------------
__global__ void bn_stats_k(const float* __restrict__ raw, float* __restrict__ stats)
{
    int c = blockIdx.x, tid = threadIdx.x;
    float s = 0.f, q = 0.f;
    for (int p = tid; p < PTS; p += 256) { float v = raw[p*CKP + c]; s += v; q += v*v; }
    __shared__ float sh[256], sh2[256];
    sh[tid]=s; sh2[tid]=q; __syncthreads();
    for (int o = 128; o; o >>= 1) { if (tid < o) { sh[tid]+=sh[tid+o]; sh2[tid]+=sh2[tid+o]; } __syncthreads(); }
    if (tid == 0) { stats[c] = sh[0]; stats[CKP + c] = sh2[0]; }
}

// ------- BN + LeakyReLU + [pos|kpf] @ Wm -> x written in SORTED order --------
__global__ void embed_k(const float* __restrict__ pos, const float* __restrict__ raw,
                        const float* __restrict__ stats, const float* __restrict__ gamma,
                        const float* __restrict__ beta, const float* __restrict__ Wm,
                        const int* __restrict__ inv,
                        float* __restrict__ xs, unsigned short* __restrict__ xsb)
{
    int p = blockIdx.x, tid = threadIdx.x;
    __shared__ float pw[67];
    if (tid < 3) pw[tid] = pos[p*3 + tid];
    else if (tid < 67) {
        int c = tid - 3;
        float mu  = stats[c] * (1.0f/PTS);
        float var = stats[CKP+c] * (1.0f/PTS) - mu*mu;
        float v = raw[p*CKP + c];
        float h = gamma[c] * (v - mu) * rsqrtf(var + EPSF) + beta[c];
        pw[tid] = h >= 0.f ? h : 0.2f * h;
    }
    __syncthreads();
    float acc = 0.f;
    for (int c = 0; c < 67; ++c) acc += pw[c] * Wm[c*FDIM + tid];
    int slot = inv[p];
    xs[(size_t)slot*FDIM + tid] = acc;
    xsb[(size_t)slot*FDIM + tid] = f2bf(acc);
}

// ------ wide-tile bf16 MFMA GEMM, 32x256 tile, optional fused LayerNorm ------
// LNM: 0 none, 1 LN (Cf fp32 + Cb bf16), 2 LN final (scatter fp32 via sorted).
template<int ACT, int LNM>
__global__ __launch_bounds__(256) void bgemm256_k(
    const unsigned short* __restrict__ A, const unsigned short* __restrict__ Wt,
    const float* __restrict__ bias, const float* __restrict__ R,
    const float* __restrict__ g, const float* __restrict__ be,
    const int* __restrict__ sorted,
    float* __restrict__ Cf, unsigned short* __restrict__ Cb,
    int Nc, int K)
{
    __shared__ unsigned short As[32*72];
    __shared__ unsigned short Bs[256*72];
    __shared__ float red_s[4][32], red_q[4][32];
    int tid = threadIdx.x;
    int l = tid & 63, wc = tid >> 6;
    int lr = l & 15, lk = l >> 4;
    int bm = blockIdx.y * 32, bn = blockIdx.x * 256;

    f32x4 acc[2][4] = {};

    for (int k0 = 0; k0 < K; k0 += 64) {
        __syncthreads();
        {
            int row = tid >> 3, seg = tid & 7;
            *(ushort8*)&As[row*72 + seg*8] =
                *(const ushort8*)&A[(size_t)(bm + row)*K + k0 + seg*8];
        }
        #pragma unroll
        for (int i = 0; i < 8; ++i) {
            int id = tid + i*256;
            int row = id >> 3, seg = id & 7;
            *(ushort8*)&Bs[row*72 + seg*8] =
                *(const ushort8*)&Wt[(size_t)(bn + row)*K + k0 + seg*8];
        }
        __syncthreads();
        #pragma unroll
        for (int kk = 0; kk < 64; kk += 32) {
            short8 a[2], b[4];
            #pragma unroll
            for (int mi = 0; mi < 2; ++mi)
                a[mi] = *(const short8*)&As[(mi*16 + lr)*72 + kk + lk*8];
            #pragma unroll
            for (int ni = 0; ni < 4; ++ni)
                b[ni] = *(const short8*)&Bs[(wc*64 + ni*16 + lr)*72 + kk + lk*8];
            #pragma unroll
            for (int mi = 0; mi < 2; ++mi)
                #pragma unroll
                for (int ni = 0; ni < 4; ++ni)
                    acc[mi][ni] = __builtin_amdgcn_mfma_f32_16x16x32_bf16(
                        a[mi], b[ni], acc[mi][ni], 0, 0, 0);
        }
    }

    #pragma unroll
    for (int mi = 0; mi < 2; ++mi) {
        #pragma unroll
        for (int r = 0; r < 4; ++r) {
            int row = bm + mi*16 + lk*4 + r;
            #pragma unroll
            for (int ni = 0; ni < 4; ++ni) {
                int col = bn + wc*64 + ni*16 + lr;
                float v = acc[mi][ni][r] + bias[col];
                if (R) v += R[(size_t)row*Nc + col];
                if (ACT == 1) v = v > 0.f ? v : 0.f;
                acc[mi][ni][r] = v;
            }
        }
    }

    if (LNM == 0) {
        #pragma unroll
        for (int mi = 0; mi < 2; ++mi)
            #pragma unroll
            for (int r = 0; r < 4; ++r) {
                int row = bm + mi*16 + lk*4 + r;
                #pragma unroll
                for (int ni = 0; ni < 4; ++ni) {
                    int col = bn + wc*64 + ni*16 + lr;
                    if (Cf) Cf[(size_t)row*Nc + col] = acc[mi][ni][r];
                    if (Cb) Cb[(size_t)row*Nc + col] = f2bf(acc[mi][ni][r]);
                }
            }
    } else {
        #pragma unroll
        for (int mi = 0; mi < 2; ++mi) {
            #pragma unroll
            for (int r = 0; r < 4; ++r) {
                float ps = 0.f, pq = 0.f;
                #pragma unroll
                for (int ni = 0; ni < 4; ++ni) { float v = acc[mi][ni][r]; ps += v; pq += v*v; }
                ps += __shfl_xor(ps, 1);  pq += __shfl_xor(pq, 1);
                ps += __shfl_xor(ps, 2);  pq += __shfl_xor(pq, 2);
                ps += __shfl_xor(ps, 4);  pq += __shfl_xor(pq, 4);
                ps += __shfl_xor(ps, 8);  pq += __shfl_xor(pq, 8);
                if (lr == 0) {
                    int rl = mi*16 + lk*4 + r;
                    red_s[wc][rl] = ps;
                    red_q[wc][rl] = pq;
                }
            }
        }
        __syncthreads();
        #pragma unroll
        for (int mi = 0; mi < 2; ++mi) {
            #pragma unroll
            for (int r = 0; r < 4; ++r) {
                int rl = mi*16 + lk*4 + r;
                float s = red_s[0][rl] + red_s[1][rl] + red_s[2][rl] + red_s[3][rl];
                float q = red_q[0][rl] + red_q[1][rl] + red_q[2][rl] + red_q[3][rl];
                float mu  = s * (1.0f/FDIM);
                float var = q * (1.0f/FDIM) - mu*mu;
                float rs  = rsqrtf(var + EPSF);
                int row = bm + rl;
                #pragma unroll
                for (int ni = 0; ni < 4; ++ni) {
                    int col = wc*64 + ni*16 + lr;
                    float o = g[col]*(acc[mi][ni][r]-mu)*rs + be[col];
                    if (LNM == 2) Cf[(size_t)sorted[row]*FDIM + col] = o;
                    else          Cf[(size_t)row*FDIM + col] = o;
                    if (Cb) Cb[(size_t)row*FDIM + col] = f2bf(o);
                }
            }
        }
    }
}

// ---------------- cluster-local MFMA attention ----------------
__global__ __launch_bounds__(512) void attn_k(
    const unsigned short* __restrict__ qkv, const int* __restrict__ offs,
    const int* __restrict__ hist, unsigned short* __restrict__ o)
{
    int cci = blockIdx.x, b = blockIdx.y;
    int Mc = hist[b*64 + cci];
    if (Mc == 0) return;
    int off = b*NPTS + offs[b*64 + cci];
    __shared__ unsigned short Kl[64*CPITCH];
    __shared__ unsigned short Vl[64*CPITCH];
    __shared__ unsigned short Pl[8][64*72];
    int tid = threadIdx.x;

    if (Mc <= 64) {
        #pragma unroll
        for (int it = 0; it < 4; ++it) {
            int id = tid + it*512;
            int key = id >> 5, ch8 = (id & 31)*8;
            ushort8 kv, vv;
            if (key < Mc) {
                kv = *(const ushort8*)&qkv[(size_t)(off+key)*768 + 256 + ch8];
                vv = *(const ushort8*)&qkv[(size_t)(off+key)*768 + 512 + ch8];
            } else {
                kv = (ushort8)0; vv = (ushort8)0;
            }
            *(ushort8*)&Kl[key*CPITCH + ch8] = kv;
            *(ushort8*)&Vl[key*CPITCH + ch8] = vv;
        }
        __syncthreads();

        int w = tid >> 6, l = tid & 63;
        int h = w;
        int lr = l & 15, lk = l >> 4;

        f32x4 s[4][4] = {};
        short8 a[4], bb[4];
        #pragma unroll
        for (int mi = 0; mi < 4; ++mi) {
            int rg = off + mi*16 + lr;
            if (rg > PTS-1) rg = PTS-1;
            a[mi] = *(const short8*)&qkv[(size_t)rg*768 + h*32 + lk*8];
        }
        #pragma unroll
        for (int ni = 0; ni < 4; ++ni)
            bb[ni] = *(const short8*)&Kl[(ni*16+lr)*CPITCH + h*32 + lk*8];
        #pragma unroll
        for (int mi = 0; mi < 4; ++mi)
            #pragma unroll
            for (int ni = 0; ni < 4; ++ni)
                s[mi][ni] = __builtin_amdgcn_mfma_f32_16x16x32_bf16(a[mi], bb[ni], s[mi][ni], 0, 0, 0);

        unsigned short* Pw = Pl[w];
        float invl[4][4];
        #pragma unroll
        for (int mi = 0; mi < 4; ++mi) {
            #pragma unroll
            for (int r = 0; r < 4; ++r) {
                int row = mi*16 + lk*4 + r;
                float sv[4]; float mx = -1e30f;
                #pragma unroll
                for (int ni = 0; ni < 4; ++ni) {
                    int col = ni*16 + lr;
                    float x = s[mi][ni][r] * SCALE;
                    sv[ni] = (col < Mc) ? x : -1e30f;
                    mx = fmaxf(mx, sv[ni]);
                }
                mx = fmaxf(mx, __shfl_xor(mx, 1));
                mx = fmaxf(mx, __shfl_xor(mx, 2));
                mx = fmaxf(mx, __shfl_xor(mx, 4));
                mx = fmaxf(mx, __shfl_xor(mx, 8));
                float ls = 0.f;
                #pragma unroll
                for (int ni = 0; ni < 4; ++ni) {
                    float e = __expf(sv[ni] - mx);
                    ls += e;
                    Pw[row*72 + ni*16 + lr] = f2bf(e);
                }
                ls += __shfl_xor(ls, 1);
                ls += __shfl_xor(ls, 2);
                ls += __shfl_xor(ls, 4);
                ls += __shfl_xor(ls, 8);
                invl[mi][r] = 1.0f / ls;
            }
        }

        f32x4 oacc[4][2] = {};
        #pragma unroll
        for (int ks = 0; ks < 2; ++ks) {
            short8 bv[2];
            #pragma unroll
            for (int db = 0; db < 2; ++db) {
                short8 t;
                #pragma unroll
                for (int e = 0; e < 8; ++e)
                    t[e] = (short)Vl[(ks*32 + lk*8 + e)*CPITCH + h*32 + db*16 + lr];
                bv[db] = t;
            }
            #pragma unroll
            for (int mi = 0; mi < 4; ++mi) {
                short8 pa = *(const short8*)&Pw[(mi*16+lr)*72 + ks*32 + lk*8];
                #pragma unroll
                for (int db = 0; db < 2; ++db)
                    oacc[mi][db] = __builtin_amdgcn_mfma_f32_16x16x32_bf16(pa, bv[db], oacc[mi][db], 0, 0, 0);
            }
        }

        #pragma unroll
        for (int mi = 0; mi < 4; ++mi)
            #pragma unroll
            for (int db = 0; db < 2; ++db)
                #pragma unroll
                for (int r = 0; r < 4; ++r) {
                    int row = mi*16 + lk*4 + r;
                    if (row < Mc)
                        o[(size_t)(off+row)*FDIM + h*32 + db*16 + lr] =
                            f2bf(oacc[mi][db][r] * invl[mi][r]);
                }
    } else {
        for (int task = tid; task < Mc*NHEAD; task += 512) {
            int row = task >> 3, h = task & 7;
            float qr[DHEAD];
            #pragma unroll
            for (int d = 0; d < DHEAD; ++d)
                qr[d] = b2f(qkv[(size_t)(off+row)*768 + h*32 + d]);
            float m = -3e38f, lsum = 0.f, acc[DHEAD];
            #pragma unroll
            for (int d = 0; d < DHEAD; ++d) acc[d] = 0.f;
            for (int j = 0; j < Mc; ++j) {
                float dot = 0.f;
                #pragma unroll
                for (int d = 0; d < DHEAD; ++d)
                    dot += qr[d] * b2f(qkv[(size_t)(off+j)*768 + 256 + h*32 + d]);
                float sc = dot * SCALE;
                float mn = fmaxf(m, sc);
                float aa = __expf(m - mn);
                float e  = __expf(sc - mn);
                lsum = lsum*aa + e;
                #pragma unroll
                for (int d = 0; d < DHEAD; ++d)
                    acc[d] = acc[d]*aa + e * b2f(qkv[(size_t)(off+j)*768 + 512 + h*32 + d]);
                m = mn;
            }
            float inv = 1.0f / lsum;
            #pragma unroll
            for (int d = 0; d < DHEAD; ++d)
                o[(size_t)(off+row)*FDIM + h*32 + d] = f2bf(acc[d]*inv);
        }
    }
}

extern "C" void kernel_launch(void* const* d_in, const int* in_sizes, int n_in,
                              void* d_out, int out_size, void* d_ws, size_t ws_size,
                              hipStream_t stream)
{
    (void)in_sizes; (void)n_in; (void)out_size; (void)ws_size;
    const float* pos  = (const float*)d_in[0];
    const float* feat = (const float*)d_in[1];
    const float* kpts = (const float*)d_in[2];
    const float* kpw  = (const float*)d_in[3];
    const float* bn_g = (const float*)d_in[4];
    const float* bn_b = (const float*)d_in[5];
    const float* Wm   = (const float*)d_in[6];
    const float* Wq   = (const float*)d_in[7];
    const float* bq   = (const float*)d_in[8];
    const float* Wk   = (const float*)d_in[9];
    const float* bk   = (const float*)d_in[10];
    const float* Wv   = (const float*)d_in[11];
    const float* bv   = (const float*)d_in[12];
    const float* Wo   = (const float*)d_in[13];
    const float* bo   = (const float*)d_in[14];
    const float* g1   = (const float*)d_in[15];
    const float* be1  = (const float*)d_in[16];
    const float* W1   = (const float*)d_in[17];
    const float* bb1  = (const float*)d_in[18];
    const float* W2   = (const float*)d_in[19];
    const float* bb2  = (const float*)d_in[20];
    const float* g2   = (const float*)d_in[21];
    const float* be2  = (const float*)d_in[22];

    char* ws = (char*)d_ws;
    const size_t MB = 1024*1024;
    float* raw    = (float*)(ws + 0);                    // 2 MB
    unsigned long long* masks = (unsigned long long*)(ws + 2*MB);  // 2 MB
    float* stats  = (float*)(ws + 4*MB);                 // 512 B
    int*   hist   = (int*)(ws + 4*MB + 4096);            // 1 KB
    int*   offs   = hist + 256;
    int*   sorted = (int*)(ws + 4*MB + 16384);           // 32 KB
    int*   inv    = sorted + PTS;                        // 32 KB
    float* xs   = (float*)(ws + 5*MB);                   // [P,256] f32 (8 MB)
    float* x2   = (float*)(ws + 13*MB);                  // [P,256] f32 (8 MB)
    unsigned short* xsb   = (unsigned short*)(ws + 21*MB);  // [P,256] bf16 (4 MB)
    unsigned short* x2b   = (unsigned short*)(ws + 25*MB);  // [P,256] bf16 (4 MB)
    unsigned short* qkvb  = (unsigned short*)(ws + 29*MB);  // [P,768] bf16 (12 MB)
    unsigned short* attnb = (unsigned short*)(ws + 41*MB);  // [P,256] bf16 (4 MB)
    unsigned short* wT    = (unsigned short*)(ws + 45*MB);  // 2 MB
    float*          bqkv  = (float*)(ws + 47*MB);           // 6 KB
    unsigned short* hb    = qkvb;                            // [P,512] aliases qkv (dead)

    prep_k<<<3594, 256, 0, stream>>>(pos, Wq, Wk, Wv, Wo, W1, W2, bq, bk, bv,
                                     wT, bqkv, sorted, inv, offs, hist, masks);
    kpc_k<<<PTS/64, 256, 0, stream>>>(pos, feat, masks, kpts, kpw, raw);
    bn_stats_k<<<CKP, 256, 0, stream>>>(raw, stats);
    embed_k<<<PTS, 256, 0, stream>>>(pos, raw, stats, bn_g, bn_b, Wm, inv, xs, xsb);

    for (int l = 0; l < NLAY; ++l) {
        bgemm256_k<0,0><<<dim3(3, PTS/32), 256, 0, stream>>>(
            xsb, wT + (size_t)l*196608, bqkv + l*768, nullptr, nullptr, nullptr, nullptr,
            nullptr, qkvb, 768, FDIM);
        attn_k<<<dim3(64, BATCH), 512, 0, stream>>>(qkvb, offs, hist, attnb);
        bgemm256_k<0,1><<<dim3(1, PTS/32), 256, 0, stream>>>(
            attnb, wT + 393216 + (size_t)l*65536, bo + l*FDIM, xs,
            g1 + l*FDIM, be1 + l*FDIM, nullptr, x2, x2b, FDIM, FDIM);
        bgemm256_k<1,0><<<dim3(2, PTS/32), 256, 0, stream>>>(
            x2b, wT + 524288 + (size_t)l*131072, bb1 + l*HIDD, nullptr, nullptr, nullptr,
            nullptr, nullptr, hb, HIDD, FDIM);
        if (l == NLAY-1)
            bgemm256_k<0,2><<<dim3(1, PTS/32), 256, 0, stream>>>(
                hb, wT + 786432 + (size_t)l*131072, bb2 + l*FDIM, x2,
                g2 + l*FDIM, be2 + l*FDIM, sorted, (float*)d_out, nullptr, FDIM, HIDD);
        else
            bgemm256_k<0,1><<<dim3(1, PTS/32), 256, 0, stream>>>(
                hb, wT + 786432 + (size_t)l*131072, bb2 + l*FDIM, x2,
                g2 + l*FDIM, be2 + l*FDIM, nullptr, xs, xsb, FDIM, HIDD);
    }
}

// Round 9
// 224.274 us; speedup vs baseline: 1.2528x; 1.0663x over previous
//
#include <hip/hip_runtime.h>
#include <math.h>

#define BATCH 4
#define NPTS  2048
#define PTS   8192      // BATCH*NPTS
#define NS    64
#define KPTS  15
#define CKP   64
#define FDIM  256
#define HIDD  512
#define NHEAD 8
#define DHEAD 32
#define NLAY  2
#define R2    0.04f
#define KPE   0.08f
#define WIN   0.25f
#define EPSF  1e-5f
#define SCALE 0.17677669529663687f   // 1/sqrt(32)
#define CPITCH 264                   // 256 + 8 pad (bank-safe)

typedef __attribute__((ext_vector_type(8))) short          short8;
typedef __attribute__((ext_vector_type(8))) unsigned short ushort8;
typedef __attribute__((ext_vector_type(4))) float          f32x4;

static __device__ __forceinline__ unsigned short f2bf(float f) {
    unsigned int u = __float_as_uint(f);
    unsigned int r = u + 0x7fffu + ((u >> 16) & 1u);   // RNE
    return (unsigned short)(r >> 16);
}
static __device__ __forceinline__ float b2f(unsigned short u) {
    return __uint_as_float(((unsigned int)u) << 16);
}

// ================= fused prep: wconv + packb + cluster + mask =================
// blocks: [0,3072) wconv | [3072,3584) mask | [3584,3588) cluster | [3588,3594) packb
__global__ __launch_bounds__(256) void prep_k(
    const float* __restrict__ pos,
    const float* __restrict__ Wq, const float* __restrict__ Wk,
    const float* __restrict__ Wv, const float* __restrict__ Wo,
    const float* __restrict__ W1, const float* __restrict__ W2,
    const float* __restrict__ bq, const float* __restrict__ bk,
    const float* __restrict__ bv,
    unsigned short* __restrict__ wT, float* __restrict__ bqkv,
    int* __restrict__ sorted, int* __restrict__ inv,
    int* __restrict__ offs, int* __restrict__ hist,
    unsigned long long* __restrict__ masks)
{
    __shared__ __align__(16) unsigned char sm[38400];
    int bid = blockIdx.x, tid = threadIdx.x;

    if (bid < 3072) {
        int z = bid >> 8, r = bid & 255;
        int bx = r & 15, by = r >> 4;
        int t = z >> 1, l = z & 1;
        const float* src; unsigned short* dst; int K, N;
        switch (t) {
            case 0: src=Wq+(size_t)l*65536;  dst=wT+(size_t)l*196608;           K=256; N=256; break;
            case 1: src=Wk+(size_t)l*65536;  dst=wT+(size_t)l*196608+65536;     K=256; N=256; break;
            case 2: src=Wv+(size_t)l*65536;  dst=wT+(size_t)l*196608+131072;    K=256; N=256; break;
            case 3: src=Wo+(size_t)l*65536;  dst=wT+393216+(size_t)l*65536;     K=256; N=256; break;
            case 4: src=W1+(size_t)l*131072; dst=wT+524288+(size_t)l*131072;    K=256; N=512; break;
            default:src=W2+(size_t)l*131072; dst=wT+786432+(size_t)l*131072;    K=512; N=256; break;
        }
        int n0 = bx*32, k0 = by*32;
        if (n0 >= N || k0 >= K) return;
        float* ld = (float*)sm;
        #pragma unroll
        for (int i = 0; i < 4; ++i) { int v=tid+i*256; int ty=v>>5, tx=v&31;
            ld[ty*33+tx] = src[(size_t)(k0+ty)*N + n0+tx]; }
        __syncthreads();
        #pragma unroll
        for (int i = 0; i < 4; ++i) { int v=tid+i*256; int ny=v>>5, nk=v&31;
            dst[(size_t)(n0+ny)*K + k0+nk] = f2bf(ld[nk*33+ny]); }
    } else if (bid < 3584) {
        int m_ = bid - 3072;
        int chunk = m_ & 31, b = (m_ >> 5) & 3, qg = m_ >> 7;
        int w = tid >> 6, lane = tid & 63;
        float* qx = (float*)sm; float* qy = qx + 512; float* qz = qy + 512;
        int qbase = qg * 512;
        for (int t = tid; t < 512; t += 256) {
            const float* q = pos + (size_t)(b*NPTS + qbase + t)*3;
            qx[t] = q[0]; qy[t] = q[1]; qz[t] = q[2];
        }
        const float* c = pos + (size_t)(b*NPTS + chunk*64 + lane)*3;
        float cx = c[0], cy = c[1], cz = c[2];
        __syncthreads();
        int q0 = w * 128;
        for (int i = 0; i < 128; ++i) {
            int qi = q0 + i;
            float dx = cx - qx[qi], dy = cy - qy[qi], dz = cz - qz[qi];
            float d2 = dx*dx + dy*dy + dz*dz;
            unsigned long long m = __ballot(d2 <= R2);
            if (lane == 0) masks[(size_t)(b*NPTS + qbase + qi)*32 + chunk] = m;
        }
    } else if (bid < 3588) {
        int b = bid - 3584;
        float* sx = (float*)sm; float* sy = sx + 256; float* sz = sy + 256;
        unsigned char* cid_s = sm + 3072;
        unsigned int* maskc = (unsigned int*)(sm + 5120);
        int* wpfx = (int*)(sm + 21504);
        int* tot  = (int*)(sm + 37888);
        int* off_c= (int*)(sm + 38144);
        float mx=1e30f, my=1e30f, mz=1e30f;
        for (int n = tid; n < NPTS; n += 256) {
            const float* q = pos + ((size_t)b*NPTS + n)*3;
            mx = fminf(mx, q[0]); my = fminf(my, q[1]); mz = fminf(mz, q[2]);
        }
        sx[tid]=mx; sy[tid]=my; sz[tid]=mz; __syncthreads();
        for (int o=128;o;o>>=1){ if(tid<o){sx[tid]=fminf(sx[tid],sx[tid+o]);sy[tid]=fminf(sy[tid],sy[tid+o]);sz[tid]=fminf(sz[tid],sz[tid+o]);} __syncthreads(); }
        float X = sx[0], Y = sy[0], Z = sz[0];
        __syncthreads();
        for (int i = tid; i < 64*64; i += 256) maskc[i] = 0u;
        __syncthreads();
        for (int n = tid; n < NPTS; n += 256) {
            const float* q = pos + ((size_t)b*NPTS + n)*3;
            int cx = (int)floorf((q[0]-X)/WIN);
            int cy = (int)floorf((q[1]-Y)/WIN);
            int cz = (int)floorf((q[2]-Z)/WIN);
            int c = (cx<<4) | (cy<<2) | cz;
            cid_s[n] = (unsigned char)c;
            atomicOr(&maskc[c*64 + (n>>5)], 1u << (n & 31));
        }
        __syncthreads();
        if (tid < 64) {
            int run = 0;
            for (int wd = 0; wd < 64; ++wd) { wpfx[tid*64+wd] = run; run += __popc(maskc[tid*64+wd]); }
            tot[tid] = run;
        }
        __syncthreads();
        if (tid == 0) { int run = 0; for (int c = 0; c < 64; ++c) { off_c[c] = run; run += tot[c]; } }
        __syncthreads();
        if (tid < 64) { hist[b*64+tid] = tot[tid]; offs[b*64+tid] = off_c[tid]; }
        for (int n = tid; n < NPTS; n += 256) {
            int c = cid_s[n];
            int wd = n >> 5;
            int rank = wpfx[c*64+wd] + __popc(maskc[c*64+wd] & ((1u << (n & 31)) - 1u));
            int slot = b*NPTS + off_c[c] + rank;
            int p = b*NPTS + n;
            sorted[slot] = p;
            inv[p] = slot;
        }
    } else {
        int i = (bid - 3588)*256 + tid;
        if (i < 2*768) {
            int l = i / 768, n = i - l*768;
            float v = (n < 256) ? bq[l*256+n] : (n < 512) ? bk[l*256+n-256] : bv[l*256+n-512];
            bqkv[l*768 + n] = v;
        }
    }
}

// ======== KPConv: select (LDS) + lane-per-point register accumulate ==========
__global__ __launch_bounds__(256) void kpc_k(
    const float* __restrict__ pos, const float* __restrict__ feat,
    const unsigned long long* __restrict__ masks,
    const float* __restrict__ kpts, const float* __restrict__ kpw,
    float* __restrict__ raw)
{
    __shared__ int   idxs[64][66];
    __shared__ float kpwl[45*64];
    __shared__ float kpl[48];
    __shared__ float wfp[64*181 + 4];

    int tid = threadIdx.x, w = tid >> 6, lane = tid & 63;
    int pb = blockIdx.x * 64;
    int b = pb >> 11;
    int base = b * NPTS;

    for (int t = tid; t < 45*64; t += 256) kpwl[t] = kpw[t];
    if (tid < 45) kpl[tid] = kpts[tid];

    int g = tid >> 5, j = tid & 31;
    for (int pp = 0; pp < 8; ++pp) {
        int lp = pp*8 + g;
        unsigned long long m = masks[(size_t)(pb + lp)*32 + j];
        int cnt = __popcll(m);
        int inc = cnt;
        #pragma unroll
        for (int off = 1; off < 32; off <<= 1) {
            int v = __shfl_up(inc, off, 32);
            if (j >= off) inc += v;
        }
        int pfx = inc - cnt;
        int total = __shfl(inc, 31, 32);
        unsigned long long mm = m; int slot = pfx;
        while (mm && slot < NS) {
            int bit = __ffsll((long long)mm) - 1;
            idxs[lp][slot++] = j*64 + bit;
            mm &= mm - 1;
        }
        int cc = total < NS ? total : NS;
        for (int s = cc + j; s < NS; s += 32) idxs[lp][s] = NPTS;
    }
    __syncthreads();

    float wf[45];
    #pragma unroll
    for (int t = 0; t < 45; ++t) wf[t] = 0.f;
    {
        int p = pb + lane;
        float xi = pos[(size_t)p*3+0], yi = pos[(size_t)p*3+1], zi = pos[(size_t)p*3+2];
        for (int n = w*16; n < w*16 + 16; ++n) {
            int id = idxs[lane][n];
            if (id < NPTS) {
                const float* pq = pos + (size_t)(base + id)*3;
                float rx = pq[0]-xi, ry = pq[1]-yi, rz = pq[2]-zi;
                const float* ff = feat + (size_t)(base + id)*3;
                float g0 = ff[0], g1 = ff[1], g2 = ff[2];
                #pragma unroll
                for (int k = 0; k < KPTS; ++k) {
                    float dx = rx - kpl[k*3+0], dy = ry - kpl[k*3+1], dz = rz - kpl[k*3+2];
                    float dist = sqrtf(dx*dx + dy*dy + dz*dz + 1e-12f);
                    float infl = fmaxf(0.f, 1.0f - dist * (1.0f/KPE));
                    wf[k*3+0] = fmaf(infl, g0, wf[k*3+0]);
                    wf[k*3+1] = fmaf(infl, g1, wf[k*3+1]);
                    wf[k*3+2] = fmaf(infl, g2, wf[k*3+2]);
                }
            }
        }
    }
    #pragma unroll
    for (int t = 0; t < 45; ++t) wfp[lane*181 + t*4 + w] = wf[t];
    __syncthreads();
    for (int i = tid; i < 64*45; i += 256) {
        int p_ = i / 45, t = i - p_*45;
        float* q = &wfp[p_*181 + t*4];
        q[0] = (q[0]+q[1]) + (q[2]+q[3]);
    }
    __syncthreads();
    {
        int c = tid & 63, pg = tid >> 6;
        float kw[45];
        #pragma unroll
        for (int t = 0; t < 45; ++t) kw[t] = kpwl[t*64 + c];
        for (int p0 = 0; p0 < 16; p0 += 4) {
            float a0=0.f, a1=0.f, a2=0.f, a3=0.f;
            int pl = pg*16 + p0;
            #pragma unroll
            for (int t = 0; t < 45; ++t) {
                a0 = fmaf(kw[t], wfp[(pl+0)*181 + t*4], a0);
                a1 = fmaf(kw[t], wfp[(pl+1)*181 + t*4], a1);
                a2 = fmaf(kw[t], wfp[(pl+2)*181 + t*4], a2);
                a3 = fmaf(kw[t], wfp[(pl+3)*181 + t*4], a3);
            }
            raw[(size_t)(pb + pl+0)*CKP + c] = a0;
            raw[(size_t)(pb + pl+1)*CKP + c] = a1;
            raw[(size_t)(pb + pl+2)*CKP + c] = a2;
            raw[(size_t)(pb + pl+3)*CKP + c] = a3;
        }
    }
}

// ---------------- BN stats ----------------
__global__ void bn_stats_k(const float* __restrict__ raw, float* __restrict__ stats)
{
    int c = blockIdx.x, tid = threadIdx.x;
    float s = 0.f, q = 0.f;
    for (int p = tid; p < PTS; p += 256) { float v = raw[p*CKP + c]; s += v; q += v*v; }
    __shared__ float sh[256], sh2[256];
    sh[tid]=s; sh2[tid]=q; __syncthreads();
    for (int o = 128; o; o >>= 1) { if (tid < o) { sh[tid]+=sh[tid+o]; sh2[tid]+=sh2[tid+o]; } __syncthreads(); }
    if (tid == 0) { stats[c] = sh[0]; stats[CKP + c] = sh2[0]; }
}

// ------- BN + LeakyReLU + [pos|kpf] @ Wm -> x written in SORTED order --------
__global__ void embed_k(const float* __restrict__ pos, const float* __restrict__ raw,
                        const float* __restrict__ stats, const float* __restrict__ gamma,
                        const float* __restrict__ beta, const float* __restrict__ Wm,
                        const int* __restrict__ inv,
                        float* __restrict__ xs, unsigned short* __restrict__ xsb)
{
    int p = blockIdx.x, tid = threadIdx.x;
    __shared__ float pw[67];
    if (tid < 3) pw[tid] = pos[p*3 + tid];
    else if (tid < 67) {
        int c = tid - 3;
        float mu  = stats[c] * (1.0f/PTS);
        float var = stats[CKP+c] * (1.0f/PTS) - mu*mu;
        float v = raw[p*CKP + c];
        float h = gamma[c] * (v - mu) * rsqrtf(var + EPSF) + beta[c];
        pw[tid] = h >= 0.f ? h : 0.2f * h;
    }
    __syncthreads();
    float acc = 0.f;
    for (int c = 0; c < 67; ++c) acc += pw[c] * Wm[c*FDIM + tid];
    int slot = inv[p];
    xs[(size_t)slot*FDIM + tid] = acc;
    xsb[(size_t)slot*FDIM + tid] = f2bf(acc);
}

// ------ wide-tile bf16 MFMA GEMM, (MR*16)x256 tile, optional fused LayerNorm --
// LNM: 0 none, 1 LN (Cf fp32 + Cb bf16), 2 LN final (scatter fp32 via sorted).
// LN paths require MR==2.
template<int ACT, int LNM, int MR>
__global__ __launch_bounds__(256) void bgemm256_k(
    const unsigned short* __restrict__ A, const unsigned short* __restrict__ Wt,
    const float* __restrict__ bias, const float* __restrict__ R,
    const float* __restrict__ g, const float* __restrict__ be,
    const int* __restrict__ sorted,
    float* __restrict__ Cf, unsigned short* __restrict__ Cb,
    int Nc, int K)
{
    __shared__ unsigned short As[MR*16*72];
    __shared__ unsigned short Bs[256*72];
    __shared__ float red_s[4][32], red_q[4][32];
    int tid = threadIdx.x;
    int l = tid & 63, wc = tid >> 6;
    int lr = l & 15, lk = l >> 4;
    int bm = blockIdx.y * (MR*16), bn = blockIdx.x * 256;

    f32x4 acc[MR][4] = {};

    for (int k0 = 0; k0 < K; k0 += 64) {
        __syncthreads();
        #pragma unroll
        for (int i = 0; i < MR/2; ++i) {
            int id = tid + i*256;
            int row = id >> 3, seg = id & 7;
            *(ushort8*)&As[row*72 + seg*8] =
                *(const ushort8*)&A[(size_t)(bm + row)*K + k0 + seg*8];
        }
        #pragma unroll
        for (int i = 0; i < 8; ++i) {
            int id = tid + i*256;
            int row = id >> 3, seg = id & 7;
            *(ushort8*)&Bs[row*72 + seg*8] =
                *(const ushort8*)&Wt[(size_t)(bn + row)*K + k0 + seg*8];
        }
        __syncthreads();
        #pragma unroll
        for (int kk = 0; kk < 64; kk += 32) {
            short8 a[MR], b[4];
            #pragma unroll
            for (int mi = 0; mi < MR; ++mi)
                a[mi] = *(const short8*)&As[(mi*16 + lr)*72 + kk + lk*8];
            #pragma unroll
            for (int ni = 0; ni < 4; ++ni)
                b[ni] = *(const short8*)&Bs[(wc*64 + ni*16 + lr)*72 + kk + lk*8];
            #pragma unroll
            for (int mi = 0; mi < MR; ++mi)
                #pragma unroll
                for (int ni = 0; ni < 4; ++ni)
                    acc[mi][ni] = __builtin_amdgcn_mfma_f32_16x16x32_bf16(
                        a[mi], b[ni], acc[mi][ni], 0, 0, 0);
        }
    }

    #pragma unroll
    for (int mi = 0; mi < MR; ++mi) {
        #pragma unroll
        for (int r = 0; r < 4; ++r) {
            int row = bm + mi*16 + lk*4 + r;
            #pragma unroll
            for (int ni = 0; ni < 4; ++ni) {
                int col = bn + wc*64 + ni*16 + lr;
                float v = acc[mi][ni][r] + bias[col];
                if (R) v += R[(size_t)row*Nc + col];
                if (ACT == 1) v = v > 0.f ? v : 0.f;
                acc[mi][ni][r] = v;
            }
        }
    }

    if (LNM == 0) {
        #pragma unroll
        for (int mi = 0; mi < MR; ++mi)
            #pragma unroll
            for (int r = 0; r < 4; ++r) {
                int row = bm + mi*16 + lk*4 + r;
                #pragma unroll
                for (int ni = 0; ni < 4; ++ni) {
                    int col = bn + wc*64 + ni*16 + lr;
                    if (Cf) Cf[(size_t)row*Nc + col] = acc[mi][ni][r];
                    if (Cb) Cb[(size_t)row*Nc + col] = f2bf(acc[mi][ni][r]);
                }
            }
    } else {
        #pragma unroll
        for (int mi = 0; mi < 2; ++mi) {
            #pragma unroll
            for (int r = 0; r < 4; ++r) {
                float ps = 0.f, pq = 0.f;
                #pragma unroll
                for (int ni = 0; ni < 4; ++ni) { float v = acc[mi][ni][r]; ps += v; pq += v*v; }
                ps += __shfl_xor(ps, 1);  pq += __shfl_xor(pq, 1);
                ps += __shfl_xor(ps, 2);  pq += __shfl_xor(pq, 2);
                ps += __shfl_xor(ps, 4);  pq += __shfl_xor(pq, 4);
                ps += __shfl_xor(ps, 8);  pq += __shfl_xor(pq, 8);
                if (lr == 0) {
                    int rl = mi*16 + lk*4 + r;
                    red_s[wc][rl] = ps;
                    red_q[wc][rl] = pq;
                }
            }
        }
        __syncthreads();
        #pragma unroll
        for (int mi = 0; mi < 2; ++mi) {
            #pragma unroll
            for (int r = 0; r < 4; ++r) {
                int rl = mi*16 + lk*4 + r;
                float s = red_s[0][rl] + red_s[1][rl] + red_s[2][rl] + red_s[3][rl];
                float q = red_q[0][rl] + red_q[1][rl] + red_q[2][rl] + red_q[3][rl];
                float mu  = s * (1.0f/FDIM);
                float var = q * (1.0f/FDIM) - mu*mu;
                float rs  = rsqrtf(var + EPSF);
                int row = bm + rl;
                #pragma unroll
                for (int ni = 0; ni < 4; ++ni) {
                    int col = wc*64 + ni*16 + lr;
                    float o = g[col]*(acc[mi][ni][r]-mu)*rs + be[col];
                    if (LNM == 2) Cf[(size_t)sorted[row]*FDIM + col] = o;
                    else          Cf[(size_t)row*FDIM + col] = o;
                    if (Cb) Cb[(size_t)row*FDIM + col] = f2bf(o);
                }
            }
        }
    }
}

// ====== fused FFN: out = LN( relu(A@W1^T+b1)@W2^T + b2 + R ) =================
// 32-row tile, full 256-out width, loop over 8 hidden chunks of 64.
// FINAL=0: Cf fp32 + Cb bf16 (dense). FINAL=1: scatter fp32 via sorted.
template<int FINAL>
__global__ __launch_bounds__(256) void ffn_k(
    const unsigned short* __restrict__ A,    // [PTS][256] bf16
    const unsigned short* __restrict__ W1T,  // [512][256] bf16
    const float* __restrict__ b1,            // [512]
    const unsigned short* __restrict__ W2T,  // [256][512] bf16
    const float* __restrict__ b2,            // [256]
    const float* __restrict__ R,             // [PTS][256] f32 residual
    const float* __restrict__ g, const float* __restrict__ be,
    const int* __restrict__ sorted,
    float* __restrict__ Cf, unsigned short* __restrict__ Cb)
{
    __shared__ unsigned short As[32*264];    // A rows, full K=256
    __shared__ unsigned short Bs1[64*264];   // W1T chunk [64 hid][256]
    __shared__ unsigned short Bs2[256*72];   // W2T chunk [256 out][64]
    __shared__ unsigned short Hs[32*72];     // hidden chunk bf16
    __shared__ float red_s[4][32], red_q[4][32];

    int tid = threadIdx.x;
    int l = tid & 63, wc = tid >> 6;
    int lr = l & 15, lk = l >> 4;
    int bm = blockIdx.x * 32;

    // stage A once: 32 rows x 256 = 1024 ushort8
    #pragma unroll
    for (int i = 0; i < 4; ++i) {
        int id = tid + i*256;
        int row = id >> 5, seg = id & 31;
        *(ushort8*)&As[row*264 + seg*8] =
            *(const ushort8*)&A[(size_t)(bm + row)*FDIM + seg*8];
    }

    f32x4 acc[2][4] = {};

    for (int hc = 0; hc < 8; ++hc) {
        __syncthreads();   // protect Bs1/Bs2/Hs overwrite; makes As visible on hc==0
        // stage W1T rows [hc*64, hc*64+64) x 256: 2048 ushort8
        #pragma unroll
        for (int i = 0; i < 8; ++i) {
            int id = tid + i*256;
            int row = id >> 5, seg = id & 31;
            *(ushort8*)&Bs1[row*264 + seg*8] =
                *(const ushort8*)&W1T[(size_t)(hc*64 + row)*FDIM + seg*8];
        }
        // stage W2T cols chunk: [256 out][hc*64..+64): 2048 ushort8
        #pragma unroll
        for (int i = 0; i < 8; ++i) {
            int id = tid + i*256;
            int row = id >> 3, seg = id & 7;
            *(ushort8*)&Bs2[row*72 + seg*8] =
                *(const ushort8*)&W2T[(size_t)row*HIDD + hc*64 + seg*8];
        }
        __syncthreads();

        // H chunk: rows 32 x hid 16 per wave (wave wc owns hidden cols wc*16..+16)
        f32x4 h[2] = {};
        #pragma unroll
        for (int kk = 0; kk < 256; kk += 32) {
            short8 bfr = *(const short8*)&Bs1[(wc*16 + lr)*264 + kk + lk*8];
            #pragma unroll
            for (int mi = 0; mi < 2; ++mi) {
                short8 a = *(const short8*)&As[(mi*16 + lr)*264 + kk + lk*8];
                h[mi] = __builtin_amdgcn_mfma_f32_16x16x32_bf16(a, bfr, h[mi], 0, 0, 0);
            }
        }
        #pragma unroll
        for (int mi = 0; mi < 2; ++mi)
            #pragma unroll
            for (int r = 0; r < 4; ++r) {
                int row = mi*16 + lk*4 + r;
                int hcol = wc*16 + lr;
                float v = h[mi][r] + b1[hc*64 + hcol];
                v = v > 0.f ? v : 0.f;
                Hs[row*72 + hcol] = f2bf(v);
            }
        __syncthreads();

        // acc += Hs(32x64) @ Bs2(256x64)^T
        #pragma unroll
        for (int kk = 0; kk < 64; kk += 32) {
            short8 pa[2], wb[4];
            #pragma unroll
            for (int mi = 0; mi < 2; ++mi)
                pa[mi] = *(const short8*)&Hs[(mi*16 + lr)*72 + kk + lk*8];
            #pragma unroll
            for (int ni = 0; ni < 4; ++ni)
                wb[ni] = *(const short8*)&Bs2[(wc*64 + ni*16 + lr)*72 + kk + lk*8];
            #pragma unroll
            for (int mi = 0; mi < 2; ++mi)
                #pragma unroll
                for (int ni = 0; ni < 4; ++ni)
                    acc[mi][ni] = __builtin_amdgcn_mfma_f32_16x16x32_bf16(
                        pa[mi], wb[ni], acc[mi][ni], 0, 0, 0);
        }
    }

    // epilogue: + b2 + residual, then LN
    #pragma unroll
    for (int mi = 0; mi < 2; ++mi) {
        #pragma unroll
        for (int r = 0; r < 4; ++r) {
            int row = bm + mi*16 + lk*4 + r;
            #pragma unroll
            for (int ni = 0; ni < 4; ++ni) {
                int col = wc*64 + ni*16 + lr;
                acc[mi][ni][r] += b2[col] + R[(size_t)row*FDIM + col];
            }
        }
    }
    #pragma unroll
    for (int mi = 0; mi < 2; ++mi) {
        #pragma unroll
        for (int r = 0; r < 4; ++r) {
            float ps = 0.f, pq = 0.f;
            #pragma unroll
            for (int ni = 0; ni < 4; ++ni) { float v = acc[mi][ni][r]; ps += v; pq += v*v; }
            ps += __shfl_xor(ps, 1);  pq += __shfl_xor(pq, 1);
            ps += __shfl_xor(ps, 2);  pq += __shfl_xor(pq, 2);
            ps += __shfl_xor(ps, 4);  pq += __shfl_xor(pq, 4);
            ps += __shfl_xor(ps, 8);  pq += __shfl_xor(pq, 8);
            if (lr == 0) {
                int rl = mi*16 + lk*4 + r;
                red_s[wc][rl] = ps;
                red_q[wc][rl] = pq;
            }
        }
    }
    __syncthreads();
    #pragma unroll
    for (int mi = 0; mi < 2; ++mi) {
        #pragma unroll
        for (int r = 0; r < 4; ++r) {
            int rl = mi*16 + lk*4 + r;
            float s = red_s[0][rl] + red_s[1][rl] + red_s[2][rl] + red_s[3][rl];
            float q = red_q[0][rl] + red_q[1][rl] + red_q[2][rl] + red_q[3][rl];
            float mu  = s * (1.0f/FDIM);
            float var = q * (1.0f/FDIM) - mu*mu;
            float rs  = rsqrtf(var + EPSF);
            int row = bm + rl;
            #pragma unroll
            for (int ni = 0; ni < 4; ++ni) {
                int col = wc*64 + ni*16 + lr;
                float o = g[col]*(acc[mi][ni][r]-mu)*rs + be[col];
                if (FINAL) Cf[(size_t)sorted[row]*FDIM + col] = o;
                else       Cf[(size_t)row*FDIM + col] = o;
                if (Cb) Cb[(size_t)row*FDIM + col] = f2bf(o);
            }
        }
    }
}

// ---------------- cluster-local MFMA attention ----------------
__global__ __launch_bounds__(512) void attn_k(
    const unsigned short* __restrict__ qkv, const int* __restrict__ offs,
    const int* __restrict__ hist, unsigned short* __restrict__ o)
{
    int cci = blockIdx.x, b = blockIdx.y;
    int Mc = hist[b*64 + cci];
    if (Mc == 0) return;
    int off = b*NPTS + offs[b*64 + cci];
    __shared__ unsigned short Kl[64*CPITCH];
    __shared__ unsigned short Vl[64*CPITCH];
    __shared__ unsigned short Pl[8][64*72];
    int tid = threadIdx.x;

    if (Mc <= 64) {
        #pragma unroll
        for (int it = 0; it < 4; ++it) {
            int id = tid + it*512;
            int key = id >> 5, ch8 = (id & 31)*8;
            ushort8 kv, vv;
            if (key < Mc) {
                kv = *(const ushort8*)&qkv[(size_t)(off+key)*768 + 256 + ch8];
                vv = *(const ushort8*)&qkv[(size_t)(off+key)*768 + 512 + ch8];
            } else {
                kv = (ushort8)0; vv = (ushort8)0;
            }
            *(ushort8*)&Kl[key*CPITCH + ch8] = kv;
            *(ushort8*)&Vl[key*CPITCH + ch8] = vv;
        }
        __syncthreads();

        int w = tid >> 6, l = tid & 63;
        int h = w;
        int lr = l & 15, lk = l >> 4;

        f32x4 s[4][4] = {};
        short8 a[4], bb[4];
        #pragma unroll
        for (int mi = 0; mi < 4; ++mi) {
            int rg = off + mi*16 + lr;
            if (rg > PTS-1) rg = PTS-1;
            a[mi] = *(const short8*)&qkv[(size_t)rg*768 + h*32 + lk*8];
        }
        #pragma unroll
        for (int ni = 0; ni < 4; ++ni)
            bb[ni] = *(const short8*)&Kl[(ni*16+lr)*CPITCH + h*32 + lk*8];
        #pragma unroll
        for (int mi = 0; mi < 4; ++mi)
            #pragma unroll
            for (int ni = 0; ni < 4; ++ni)
                s[mi][ni] = __builtin_amdgcn_mfma_f32_16x16x32_bf16(a[mi], bb[ni], s[mi][ni], 0, 0, 0);

        unsigned short* Pw = Pl[w];
        float invl[4][4];
        #pragma unroll
        for (int mi = 0; mi < 4; ++mi) {
            #pragma unroll
            for (int r = 0; r < 4; ++r) {
                int row = mi*16 + lk*4 + r;
                float sv[4]; float mx = -1e30f;
                #pragma unroll
                for (int ni = 0; ni < 4; ++ni) {
                    int col = ni*16 + lr;
                    float x = s[mi][ni][r] * SCALE;
                    sv[ni] = (col < Mc) ? x : -1e30f;
                    mx = fmaxf(mx, sv[ni]);
                }
                mx = fmaxf(mx, __shfl_xor(mx, 1));
                mx = fmaxf(mx, __shfl_xor(mx, 2));
                mx = fmaxf(mx, __shfl_xor(mx, 4));
                mx = fmaxf(mx, __shfl_xor(mx, 8));
                float ls = 0.f;
                #pragma unroll
                for (int ni = 0; ni < 4; ++ni) {
                    float e = __expf(sv[ni] - mx);
                    ls += e;
                    Pw[row*72 + ni*16 + lr] = f2bf(e);
                }
                ls += __shfl_xor(ls, 1);
                ls += __shfl_xor(ls, 2);
                ls += __shfl_xor(ls, 4);
                ls += __shfl_xor(ls, 8);
                invl[mi][r] = 1.0f / ls;
            }
        }

        f32x4 oacc[4][2] = {};
        #pragma unroll
        for (int ks = 0; ks < 2; ++ks) {
            short8 bv[2];
            #pragma unroll
            for (int db = 0; db < 2; ++db) {
                short8 t;
                #pragma unroll
                for (int e = 0; e < 8; ++e)
                    t[e] = (short)Vl[(ks*32 + lk*8 + e)*CPITCH + h*32 + db*16 + lr];
                bv[db] = t;
            }
            #pragma unroll
            for (int mi = 0; mi < 4; ++mi) {
                short8 pa = *(const short8*)&Pw[(mi*16+lr)*72 + ks*32 + lk*8];
                #pragma unroll
                for (int db = 0; db < 2; ++db)
                    oacc[mi][db] = __builtin_amdgcn_mfma_f32_16x16x32_bf16(pa, bv[db], oacc[mi][db], 0, 0, 0);
            }
        }

        #pragma unroll
        for (int mi = 0; mi < 4; ++mi)
            #pragma unroll
            for (int db = 0; db < 2; ++db)
                #pragma unroll
                for (int r = 0; r < 4; ++r) {
                    int row = mi*16 + lk*4 + r;
                    if (row < Mc)
                        o[(size_t)(off+row)*FDIM + h*32 + db*16 + lr] =
                            f2bf(oacc[mi][db][r] * invl[mi][r]);
                }
    } else {
        for (int task = tid; task < Mc*NHEAD; task += 512) {
            int row = task >> 3, h = task & 7;
            float qr[DHEAD];
            #pragma unroll
            for (int d = 0; d < DHEAD; ++d)
                qr[d] = b2f(qkv[(size_t)(off+row)*768 + h*32 + d]);
            float m = -3e38f, lsum = 0.f, acc[DHEAD];
            #pragma unroll
            for (int d = 0; d < DHEAD; ++d) acc[d] = 0.f;
            for (int j = 0; j < Mc; ++j) {
                float dot = 0.f;
                #pragma unroll
                for (int d = 0; d < DHEAD; ++d)
                    dot += qr[d] * b2f(qkv[(size_t)(off+j)*768 + 256 + h*32 + d]);
                float sc = dot * SCALE;
                float mn = fmaxf(m, sc);
                float aa = __expf(m - mn);
                float e  = __expf(sc - mn);
                lsum = lsum*aa + e;
                #pragma unroll
                for (int d = 0; d < DHEAD; ++d)
                    acc[d] = acc[d]*aa + e * b2f(qkv[(size_t)(off+j)*768 + 512 + h*32 + d]);
                m = mn;
            }
            float inv = 1.0f / lsum;
            #pragma unroll
            for (int d = 0; d < DHEAD; ++d)
                o[(size_t)(off+row)*FDIM + h*32 + d] = f2bf(acc[d]*inv);
        }
    }
}

extern "C" void kernel_launch(void* const* d_in, const int* in_sizes, int n_in,
                              void* d_out, int out_size, void* d_ws, size_t ws_size,
                              hipStream_t stream)
{
    (void)in_sizes; (void)n_in; (void)out_size; (void)ws_size;
    const float* pos  = (const float*)d_in[0];
    const float* feat = (const float*)d_in[1];
    const float* kpts = (const float*)d_in[2];
    const float* kpw  = (const float*)d_in[3];
    const float* bn_g = (const float*)d_in[4];
    const float* bn_b = (const float*)d_in[5];
    const float* Wm   = (const float*)d_in[6];
    const float* Wq   = (const float*)d_in[7];
    const float* bq   = (const float*)d_in[8];
    const float* Wk   = (const float*)d_in[9];
    const float* bk   = (const float*)d_in[10];
    const float* Wv   = (const float*)d_in[11];
    const float* bv   = (const float*)d_in[12];
    const float* Wo   = (const float*)d_in[13];
    const float* bo   = (const float*)d_in[14];
    const float* g1   = (const float*)d_in[15];
    const float* be1  = (const float*)d_in[16];
    const float* W1   = (const float*)d_in[17];
    const float* bb1  = (const float*)d_in[18];
    const float* W2   = (const float*)d_in[19];
    const float* bb2  = (const float*)d_in[20];
    const float* g2   = (const float*)d_in[21];
    const float* be2  = (const float*)d_in[22];

    char* ws = (char*)d_ws;
    const size_t MB = 1024*1024;
    float* raw    = (float*)(ws + 0);                    // 2 MB
    unsigned long long* masks = (unsigned long long*)(ws + 2*MB);  // 2 MB
    float* stats  = (float*)(ws + 4*MB);                 // 512 B
    int*   hist   = (int*)(ws + 4*MB + 4096);            // 1 KB
    int*   offs   = hist + 256;
    int*   sorted = (int*)(ws + 4*MB + 16384);           // 32 KB
    int*   inv    = sorted + PTS;                        // 32 KB
    float* xs   = (float*)(ws + 5*MB);                   // [P,256] f32 (8 MB)
    float* x2   = (float*)(ws + 13*MB);                  // [P,256] f32 (8 MB)
    unsigned short* xsb   = (unsigned short*)(ws + 21*MB);  // [P,256] bf16 (4 MB)
    unsigned short* x2b   = (unsigned short*)(ws + 25*MB);  // [P,256] bf16 (4 MB)
    unsigned short* qkvb  = (unsigned short*)(ws + 29*MB);  // [P,768] bf16 (12 MB)
    unsigned short* attnb = (unsigned short*)(ws + 41*MB);  // [P,256] bf16 (4 MB)
    unsigned short* wT    = (unsigned short*)(ws + 45*MB);  // 2 MB
    float*          bqkv  = (float*)(ws + 47*MB);           // 6 KB

    prep_k<<<3594, 256, 0, stream>>>(pos, Wq, Wk, Wv, Wo, W1, W2, bq, bk, bv,
                                     wT, bqkv, sorted, inv, offs, hist, masks);
    kpc_k<<<PTS/64, 256, 0, stream>>>(pos, feat, masks, kpts, kpw, raw);
    bn_stats_k<<<CKP, 256, 0, stream>>>(raw, stats);
    embed_k<<<PTS, 256, 0, stream>>>(pos, raw, stats, bn_g, bn_b, Wm, inv, xs, xsb);

    for (int l = 0; l < NLAY; ++l) {
        const unsigned short* W1T_l = wT + 524288 + (size_t)l*131072;
        const unsigned short* W2T_l = wT + 786432 + (size_t)l*131072;
        // fused QKV projection: [P,256] @ [256,768], 64-row tiles
        bgemm256_k<0,0,4><<<dim3(3, PTS/64), 256, 0, stream>>>(
            xsb, wT + (size_t)l*196608, bqkv + l*768, nullptr, nullptr, nullptr, nullptr,
            nullptr, qkvb, 768, FDIM);
        attn_k<<<dim3(64, BATCH), 512, 0, stream>>>(qkvb, offs, hist, attnb);
        // O-proj + residual + LN1 -> x2 (f32) + x2b (bf16)
        bgemm256_k<0,1,2><<<dim3(1, PTS/32), 256, 0, stream>>>(
            attnb, wT + 393216 + (size_t)l*65536, bo + l*FDIM, xs,
            g1 + l*FDIM, be1 + l*FDIM, nullptr, x2, x2b, FDIM, FDIM);
        // fused FFN + residual + LN2
        if (l == NLAY-1)
            ffn_k<1><<<PTS/32, 256, 0, stream>>>(
                x2b, W1T_l, bb1 + l*HIDD, W2T_l, bb2 + l*FDIM, x2,
                g2 + l*FDIM, be2 + l*FDIM, sorted, (float*)d_out, nullptr);
        else
            ffn_k<0><<<PTS/32, 256, 0, stream>>>(
                x2b, W1T_l, bb1 + l*HIDD, W2T_l, bb2 + l*FDIM, x2,
                g2 + l*FDIM, be2 + l*FDIM, nullptr, xs, xsb);
    }
}

// Round 10
// 209.988 us; speedup vs baseline: 1.3381x; 1.0680x over previous
//
#include <hip/hip_runtime.h>
#include <math.h>

#define BATCH 4
#define NPTS  2048
#define PTS   8192      // BATCH*NPTS
#define NS    64
#define KPTS  15
#define CKP   64
#define FDIM  256
#define HIDD  512
#define NHEAD 8
#define DHEAD 32
#define NLAY  2
#define R2    0.04f
#define KPE   0.08f
#define WIN   0.25f
#define EPSF  1e-5f
#define SCALE 0.17677669529663687f   // 1/sqrt(32)
#define CPITCH 264                   // 256 + 8 pad (bank-safe)

typedef __attribute__((ext_vector_type(8))) short          short8;
typedef __attribute__((ext_vector_type(8))) unsigned short ushort8;
typedef __attribute__((ext_vector_type(4))) float          f32x4;

static __device__ __forceinline__ unsigned short f2bf(float f) {
    unsigned int u = __float_as_uint(f);
    unsigned int r = u + 0x7fffu + ((u >> 16) & 1u);   // RNE
    return (unsigned short)(r >> 16);
}
static __device__ __forceinline__ float b2f(unsigned short u) {
    return __uint_as_float(((unsigned int)u) << 16);
}

// ================= fused prep: wconv + packb + cluster + mask =================
// blocks: [0,3072) wconv | [3072,3584) mask | [3584,3588) cluster | [3588,3594) packb
__global__ __launch_bounds__(256) void prep_k(
    const float* __restrict__ pos,
    const float* __restrict__ Wq, const float* __restrict__ Wk,
    const float* __restrict__ Wv, const float* __restrict__ Wo,
    const float* __restrict__ W1, const float* __restrict__ W2,
    const float* __restrict__ bq, const float* __restrict__ bk,
    const float* __restrict__ bv,
    unsigned short* __restrict__ wT, float* __restrict__ bqkv,
    int* __restrict__ sorted, int* __restrict__ inv,
    int* __restrict__ offs, int* __restrict__ hist,
    unsigned long long* __restrict__ masks)
{
    __shared__ __align__(16) unsigned char sm[38400];
    int bid = blockIdx.x, tid = threadIdx.x;

    if (bid < 3072) {
        int z = bid >> 8, r = bid & 255;
        int bx = r & 15, by = r >> 4;
        int t = z >> 1, l = z & 1;
        const float* src; unsigned short* dst; int K, N;
        switch (t) {
            case 0: src=Wq+(size_t)l*65536;  dst=wT+(size_t)l*196608;           K=256; N=256; break;
            case 1: src=Wk+(size_t)l*65536;  dst=wT+(size_t)l*196608+65536;     K=256; N=256; break;
            case 2: src=Wv+(size_t)l*65536;  dst=wT+(size_t)l*196608+131072;    K=256; N=256; break;
            case 3: src=Wo+(size_t)l*65536;  dst=wT+393216+(size_t)l*65536;     K=256; N=256; break;
            case 4: src=W1+(size_t)l*131072; dst=wT+524288+(size_t)l*131072;    K=256; N=512; break;
            default:src=W2+(size_t)l*131072; dst=wT+786432+(size_t)l*131072;    K=512; N=256; break;
        }
        int n0 = bx*32, k0 = by*32;
        if (n0 >= N || k0 >= K) return;
        float* ld = (float*)sm;
        #pragma unroll
        for (int i = 0; i < 4; ++i) { int v=tid+i*256; int ty=v>>5, tx=v&31;
            ld[ty*33+tx] = src[(size_t)(k0+ty)*N + n0+tx]; }
        __syncthreads();
        #pragma unroll
        for (int i = 0; i < 4; ++i) { int v=tid+i*256; int ny=v>>5, nk=v&31;
            dst[(size_t)(n0+ny)*K + k0+nk] = f2bf(ld[nk*33+ny]); }
    } else if (bid < 3584) {
        int m_ = bid - 3072;
        int chunk = m_ & 31, b = (m_ >> 5) & 3, qg = m_ >> 7;
        int w = tid >> 6, lane = tid & 63;
        float* qx = (float*)sm; float* qy = qx + 512; float* qz = qy + 512;
        int qbase = qg * 512;
        for (int t = tid; t < 512; t += 256) {
            const float* q = pos + (size_t)(b*NPTS + qbase + t)*3;
            qx[t] = q[0]; qy[t] = q[1]; qz[t] = q[2];
        }
        const float* c = pos + (size_t)(b*NPTS + chunk*64 + lane)*3;
        float cx = c[0], cy = c[1], cz = c[2];
        __syncthreads();
        int q0 = w * 128;
        for (int i = 0; i < 128; ++i) {
            int qi = q0 + i;
            float dx = cx - qx[qi], dy = cy - qy[qi], dz = cz - qz[qi];
            float d2 = dx*dx + dy*dy + dz*dz;
            unsigned long long m = __ballot(d2 <= R2);
            if (lane == 0) masks[(size_t)(b*NPTS + qbase + qi)*32 + chunk] = m;
        }
    } else if (bid < 3588) {
        int b = bid - 3584;
        float* sx = (float*)sm; float* sy = sx + 256; float* sz = sy + 256;
        unsigned char* cid_s = sm + 3072;
        unsigned int* maskc = (unsigned int*)(sm + 5120);
        int* wpfx = (int*)(sm + 21504);
        int* tot  = (int*)(sm + 37888);
        int* off_c= (int*)(sm + 38144);
        float mx=1e30f, my=1e30f, mz=1e30f;
        for (int n = tid; n < NPTS; n += 256) {
            const float* q = pos + ((size_t)b*NPTS + n)*3;
            mx = fminf(mx, q[0]); my = fminf(my, q[1]); mz = fminf(mz, q[2]);
        }
        sx[tid]=mx; sy[tid]=my; sz[tid]=mz; __syncthreads();
        for (int o=128;o;o>>=1){ if(tid<o){sx[tid]=fminf(sx[tid],sx[tid+o]);sy[tid]=fminf(sy[tid],sy[tid+o]);sz[tid]=fminf(sz[tid],sz[tid+o]);} __syncthreads(); }
        float X = sx[0], Y = sy[0], Z = sz[0];
        __syncthreads();
        for (int i = tid; i < 64*64; i += 256) maskc[i] = 0u;
        __syncthreads();
        for (int n = tid; n < NPTS; n += 256) {
            const float* q = pos + ((size_t)b*NPTS + n)*3;
            int cx = (int)floorf((q[0]-X)/WIN);
            int cy = (int)floorf((q[1]-Y)/WIN);
            int cz = (int)floorf((q[2]-Z)/WIN);
            int c = (cx<<4) | (cy<<2) | cz;
            cid_s[n] = (unsigned char)c;
            atomicOr(&maskc[c*64 + (n>>5)], 1u << (n & 31));
        }
        __syncthreads();
        if (tid < 64) {
            int run = 0;
            for (int wd = 0; wd < 64; ++wd) { wpfx[tid*64+wd] = run; run += __popc(maskc[tid*64+wd]); }
            tot[tid] = run;
        }
        __syncthreads();
        if (tid == 0) { int run = 0; for (int c = 0; c < 64; ++c) { off_c[c] = run; run += tot[c]; } }
        __syncthreads();
        if (tid < 64) { hist[b*64+tid] = tot[tid]; offs[b*64+tid] = off_c[tid]; }
        for (int n = tid; n < NPTS; n += 256) {
            int c = cid_s[n];
            int wd = n >> 5;
            int rank = wpfx[c*64+wd] + __popc(maskc[c*64+wd] & ((1u << (n & 31)) - 1u));
            int slot = b*NPTS + off_c[c] + rank;
            int p = b*NPTS + n;
            sorted[slot] = p;
            inv[p] = slot;
        }
    } else {
        int i = (bid - 3588)*256 + tid;
        if (i < 2*768) {
            int l = i / 768, n = i - l*768;
            float v = (n < 256) ? bq[l*256+n] : (n < 512) ? bk[l*256+n-256] : bv[l*256+n-512];
            bqkv[l*768 + n] = v;
        }
    }
}

// ======== KPConv: select (LDS) + lane-per-point register accumulate ==========
__global__ __launch_bounds__(256) void kpc_k(
    const float* __restrict__ pos, const float* __restrict__ feat,
    const unsigned long long* __restrict__ masks,
    const float* __restrict__ kpts, const float* __restrict__ kpw,
    float* __restrict__ raw)
{
    __shared__ int   idxs[64][66];
    __shared__ float kpwl[45*64];
    __shared__ float kpl[48];
    __shared__ float wfp[64*181 + 4];

    int tid = threadIdx.x, w = tid >> 6, lane = tid & 63;
    int pb = blockIdx.x * 64;
    int b = pb >> 11;
    int base = b * NPTS;

    for (int t = tid; t < 45*64; t += 256) kpwl[t] = kpw[t];
    if (tid < 45) kpl[tid] = kpts[tid];

    int g = tid >> 5, j = tid & 31;
    for (int pp = 0; pp < 8; ++pp) {
        int lp = pp*8 + g;
        unsigned long long m = masks[(size_t)(pb + lp)*32 + j];
        int cnt = __popcll(m);
        int inc = cnt;
        #pragma unroll
        for (int off = 1; off < 32; off <<= 1) {
            int v = __shfl_up(inc, off, 32);
            if (j >= off) inc += v;
        }
        int pfx = inc - cnt;
        int total = __shfl(inc, 31, 32);
        unsigned long long mm = m; int slot = pfx;
        while (mm && slot < NS) {
            int bit = __ffsll((long long)mm) - 1;
            idxs[lp][slot++] = j*64 + bit;
            mm &= mm - 1;
        }
        int cc = total < NS ? total : NS;
        for (int s = cc + j; s < NS; s += 32) idxs[lp][s] = NPTS;
    }
    __syncthreads();

    float wf[45];
    #pragma unroll
    for (int t = 0; t < 45; ++t) wf[t] = 0.f;
    {
        int p = pb + lane;
        float xi = pos[(size_t)p*3+0], yi = pos[(size_t)p*3+1], zi = pos[(size_t)p*3+2];
        for (int n = w*16; n < w*16 + 16; ++n) {
            int id = idxs[lane][n];
            if (id < NPTS) {
                const float* pq = pos + (size_t)(base + id)*3;
                float rx = pq[0]-xi, ry = pq[1]-yi, rz = pq[2]-zi;
                const float* ff = feat + (size_t)(base + id)*3;
                float g0 = ff[0], g1 = ff[1], g2 = ff[2];
                #pragma unroll
                for (int k = 0; k < KPTS; ++k) {
                    float dx = rx - kpl[k*3+0], dy = ry - kpl[k*3+1], dz = rz - kpl[k*3+2];
                    float dist = sqrtf(dx*dx + dy*dy + dz*dz + 1e-12f);
                    float infl = fmaxf(0.f, 1.0f - dist * (1.0f/KPE));
                    wf[k*3+0] = fmaf(infl, g0, wf[k*3+0]);
                    wf[k*3+1] = fmaf(infl, g1, wf[k*3+1]);
                    wf[k*3+2] = fmaf(infl, g2, wf[k*3+2]);
                }
            }
        }
    }
    #pragma unroll
    for (int t = 0; t < 45; ++t) wfp[lane*181 + t*4 + w] = wf[t];
    __syncthreads();
    for (int i = tid; i < 64*45; i += 256) {
        int p_ = i / 45, t = i - p_*45;
        float* q = &wfp[p_*181 + t*4];
        q[0] = (q[0]+q[1]) + (q[2]+q[3]);
    }
    __syncthreads();
    {
        int c = tid & 63, pg = tid >> 6;
        float kw[45];
        #pragma unroll
        for (int t = 0; t < 45; ++t) kw[t] = kpwl[t*64 + c];
        for (int p0 = 0; p0 < 16; p0 += 4) {
            float a0=0.f, a1=0.f, a2=0.f, a3=0.f;
            int pl = pg*16 + p0;
            #pragma unroll
            for (int t = 0; t < 45; ++t) {
                a0 = fmaf(kw[t], wfp[(pl+0)*181 + t*4], a0);
                a1 = fmaf(kw[t], wfp[(pl+1)*181 + t*4], a1);
                a2 = fmaf(kw[t], wfp[(pl+2)*181 + t*4], a2);
                a3 = fmaf(kw[t], wfp[(pl+3)*181 + t*4], a3);
            }
            raw[(size_t)(pb + pl+0)*CKP + c] = a0;
            raw[(size_t)(pb + pl+1)*CKP + c] = a1;
            raw[(size_t)(pb + pl+2)*CKP + c] = a2;
            raw[(size_t)(pb + pl+3)*CKP + c] = a3;
        }
    }
}

// ---------------- BN stats ----------------
__global__ void bn_stats_k(const float* __restrict__ raw, float* __restrict__ stats)
{
    int c = blockIdx.x, tid = threadIdx.x;
    float s = 0.f, q = 0.f;
    for (int p = tid; p < PTS; p += 256) { float v = raw[p*CKP + c]; s += v; q += v*v; }
    __shared__ float sh[256], sh2[256];
    sh[tid]=s; sh2[tid]=q; __syncthreads();
    for (int o = 128; o; o >>= 1) { if (tid < o) { sh[tid]+=sh[tid+o]; sh2[tid]+=sh2[tid+o]; } __syncthreads(); }
    if (tid == 0) { stats[c] = sh[0]; stats[CKP + c] = sh2[0]; }
}

// ------- BN + LeakyReLU + [pos|kpf] @ Wm -> x written in SORTED order --------
__global__ void embed_k(const float* __restrict__ pos, const float* __restrict__ raw,
                        const float* __restrict__ stats, const float* __restrict__ gamma,
                        const float* __restrict__ beta, const float* __restrict__ Wm,
                        const int* __restrict__ inv,
                        float* __restrict__ xs, unsigned short* __restrict__ xsb)
{
    int p = blockIdx.x, tid = threadIdx.x;
    __shared__ float pw[67];
    if (tid < 3) pw[tid] = pos[p*3 + tid];
    else if (tid < 67) {
        int c = tid - 3;
        float mu  = stats[c] * (1.0f/PTS);
        float var = stats[CKP+c] * (1.0f/PTS) - mu*mu;
        float v = raw[p*CKP + c];
        float h = gamma[c] * (v - mu) * rsqrtf(var + EPSF) + beta[c];
        pw[tid] = h >= 0.f ? h : 0.2f * h;
    }
    __syncthreads();
    float acc = 0.f;
    for (int c = 0; c < 67; ++c) acc += pw[c] * Wm[c*FDIM + tid];
    int slot = inv[p];
    xs[(size_t)slot*FDIM + tid] = acc;
    xsb[(size_t)slot*FDIM + tid] = f2bf(acc);
}

// ------ wide-tile bf16 MFMA GEMM (no-LN variant used for QKV) ----------------
template<int ACT, int MR>
__global__ __launch_bounds__(256) void bgemm256_k(
    const unsigned short* __restrict__ A, const unsigned short* __restrict__ Wt,
    const float* __restrict__ bias,
    unsigned short* __restrict__ Cb,
    int Nc, int K)
{
    __shared__ unsigned short As[MR*16*72];
    __shared__ unsigned short Bs[256*72];
    int tid = threadIdx.x;
    int l = tid & 63, wc = tid >> 6;
    int lr = l & 15, lk = l >> 4;
    int bm = blockIdx.y * (MR*16), bn = blockIdx.x * 256;

    f32x4 acc[MR][4] = {};

    for (int k0 = 0; k0 < K; k0 += 64) {
        __syncthreads();
        #pragma unroll
        for (int i = 0; i < MR/2; ++i) {
            int id = tid + i*256;
            int row = id >> 3, seg = id & 7;
            *(ushort8*)&As[row*72 + seg*8] =
                *(const ushort8*)&A[(size_t)(bm + row)*K + k0 + seg*8];
        }
        #pragma unroll
        for (int i = 0; i < 8; ++i) {
            int id = tid + i*256;
            int row = id >> 3, seg = id & 7;
            *(ushort8*)&Bs[row*72 + seg*8] =
                *(const ushort8*)&Wt[(size_t)(bn + row)*K + k0 + seg*8];
        }
        __syncthreads();
        #pragma unroll
        for (int kk = 0; kk < 64; kk += 32) {
            short8 a[MR], b[4];
            #pragma unroll
            for (int mi = 0; mi < MR; ++mi)
                a[mi] = *(const short8*)&As[(mi*16 + lr)*72 + kk + lk*8];
            #pragma unroll
            for (int ni = 0; ni < 4; ++ni)
                b[ni] = *(const short8*)&Bs[(wc*64 + ni*16 + lr)*72 + kk + lk*8];
            #pragma unroll
            for (int mi = 0; mi < MR; ++mi)
                #pragma unroll
                for (int ni = 0; ni < 4; ++ni)
                    acc[mi][ni] = __builtin_amdgcn_mfma_f32_16x16x32_bf16(
                        a[mi], b[ni], acc[mi][ni], 0, 0, 0);
        }
    }

    #pragma unroll
    for (int mi = 0; mi < MR; ++mi) {
        #pragma unroll
        for (int r = 0; r < 4; ++r) {
            int row = bm + mi*16 + lk*4 + r;
            #pragma unroll
            for (int ni = 0; ni < 4; ++ni) {
                int col = bn + wc*64 + ni*16 + lr;
                float v = acc[mi][ni][r] + bias[col];
                if (ACT == 1) v = v > 0.f ? v : 0.f;
                Cb[(size_t)row*Nc + col] = f2bf(v);
            }
        }
    }
}

// ====== fused attention + O-proj + residual + LN1 ===========================
// grid (64 clusters, BATCH), 512 threads = 8 waves.
__global__ __launch_bounds__(512) void attn2_k(
    const unsigned short* __restrict__ qkv, const unsigned short* __restrict__ WoT,
    const float* __restrict__ bo, const float* __restrict__ xs,
    const float* __restrict__ g, const float* __restrict__ be,
    const int* __restrict__ offs, const int* __restrict__ hist,
    float* __restrict__ x2, unsigned short* __restrict__ x2b)
{
    int cci = blockIdx.x, b = blockIdx.y;
    int Mc = hist[b*64 + cci];
    if (Mc == 0) return;
    int off = b*NPTS + offs[b*64 + cci];

    __shared__ unsigned short Kl[64*CPITCH];   // reused as Ol
    __shared__ unsigned short Vl[64*CPITCH];   // reused as red_s/red_q
    __shared__ unsigned short Pl[8][64*72];    // reused as Bs (WoT K-chunk)

    unsigned short* Ol = Kl;
    unsigned short* Bs = &Pl[0][0];
    float* red_s = (float*)Vl;                 // [8][64]
    float* red_q = red_s + 512;

    int tid = threadIdx.x;
    int w = tid >> 6, l = tid & 63;
    int lr = l & 15, lk = l >> 4;

    for (int r0 = 0; r0 < Mc; r0 += 64) {
        int nr = (Mc - r0) < 64 ? (Mc - r0) : 64;

        if (Mc <= 64) {
            // ---- fast path: MFMA attention, O into Ol ----
            #pragma unroll
            for (int it = 0; it < 4; ++it) {
                int id = tid + it*512;
                int key = id >> 5, ch8 = (id & 31)*8;
                ushort8 kv, vv;
                if (key < Mc) {
                    kv = *(const ushort8*)&qkv[(size_t)(off+key)*768 + 256 + ch8];
                    vv = *(const ushort8*)&qkv[(size_t)(off+key)*768 + 512 + ch8];
                } else {
                    kv = (ushort8)0; vv = (ushort8)0;
                }
                *(ushort8*)&Kl[key*CPITCH + ch8] = kv;
                *(ushort8*)&Vl[key*CPITCH + ch8] = vv;
            }
            __syncthreads();

            int h = w;
            f32x4 s[4][4] = {};
            short8 a[4], bb[4];
            #pragma unroll
            for (int mi = 0; mi < 4; ++mi) {
                int rg = off + mi*16 + lr;
                if (rg > PTS-1) rg = PTS-1;
                a[mi] = *(const short8*)&qkv[(size_t)rg*768 + h*32 + lk*8];
            }
            #pragma unroll
            for (int ni = 0; ni < 4; ++ni)
                bb[ni] = *(const short8*)&Kl[(ni*16+lr)*CPITCH + h*32 + lk*8];
            #pragma unroll
            for (int mi = 0; mi < 4; ++mi)
                #pragma unroll
                for (int ni = 0; ni < 4; ++ni)
                    s[mi][ni] = __builtin_amdgcn_mfma_f32_16x16x32_bf16(a[mi], bb[ni], s[mi][ni], 0, 0, 0);

            unsigned short* Pw = Pl[w];
            float invl[4][4];
            #pragma unroll
            for (int mi = 0; mi < 4; ++mi) {
                #pragma unroll
                for (int r = 0; r < 4; ++r) {
                    int row = mi*16 + lk*4 + r;
                    float sv[4]; float mx = -1e30f;
                    #pragma unroll
                    for (int ni = 0; ni < 4; ++ni) {
                        int col = ni*16 + lr;
                        float x = s[mi][ni][r] * SCALE;
                        sv[ni] = (col < Mc) ? x : -1e30f;
                        mx = fmaxf(mx, sv[ni]);
                    }
                    mx = fmaxf(mx, __shfl_xor(mx, 1));
                    mx = fmaxf(mx, __shfl_xor(mx, 2));
                    mx = fmaxf(mx, __shfl_xor(mx, 4));
                    mx = fmaxf(mx, __shfl_xor(mx, 8));
                    float ls = 0.f;
                    #pragma unroll
                    for (int ni = 0; ni < 4; ++ni) {
                        float e = __expf(sv[ni] - mx);
                        ls += e;
                        Pw[row*72 + ni*16 + lr] = f2bf(e);
                    }
                    ls += __shfl_xor(ls, 1);
                    ls += __shfl_xor(ls, 2);
                    ls += __shfl_xor(ls, 4);
                    ls += __shfl_xor(ls, 8);
                    invl[mi][r] = 1.0f / ls;
                }
            }

            f32x4 oacc[4][2] = {};
            #pragma unroll
            for (int ks = 0; ks < 2; ++ks) {
                short8 bv[2];
                #pragma unroll
                for (int db = 0; db < 2; ++db) {
                    short8 t;
                    #pragma unroll
                    for (int e = 0; e < 8; ++e)
                        t[e] = (short)Vl[(ks*32 + lk*8 + e)*CPITCH + h*32 + db*16 + lr];
                    bv[db] = t;
                }
                #pragma unroll
                for (int mi = 0; mi < 4; ++mi) {
                    short8 pa = *(const short8*)&Pw[(mi*16+lr)*72 + ks*32 + lk*8];
                    #pragma unroll
                    for (int db = 0; db < 2; ++db)
                        oacc[mi][db] = __builtin_amdgcn_mfma_f32_16x16x32_bf16(pa, bv[db], oacc[mi][db], 0, 0, 0);
                }
            }
            __syncthreads();   // everyone done reading Kl/Vl/Pl
            #pragma unroll
            for (int mi = 0; mi < 4; ++mi)
                #pragma unroll
                for (int db = 0; db < 2; ++db)
                    #pragma unroll
                    for (int r = 0; r < 4; ++r) {
                        int row = mi*16 + lk*4 + r;
                        Ol[row*CPITCH + h*32 + db*16 + lr] =
                            f2bf(oacc[mi][db][r] * invl[mi][r]);
                    }
        } else {
            // ---- serial fallback: rows [r0, r0+nr) into Ol ----
            __syncthreads();   // protect Ol/Bs from previous chunk's readers
            for (int task = tid; task < nr*NHEAD; task += 512) {
                int row = task >> 3, h = task & 7;
                float qr[DHEAD];
                #pragma unroll
                for (int d = 0; d < DHEAD; ++d)
                    qr[d] = b2f(qkv[(size_t)(off+r0+row)*768 + h*32 + d]);
                float m = -3e38f, lsum = 0.f, acc[DHEAD];
                #pragma unroll
                for (int d = 0; d < DHEAD; ++d) acc[d] = 0.f;
                for (int jj = 0; jj < Mc; ++jj) {
                    float dot = 0.f;
                    #pragma unroll
                    for (int d = 0; d < DHEAD; ++d)
                        dot += qr[d] * b2f(qkv[(size_t)(off+jj)*768 + 256 + h*32 + d]);
                    float sc = dot * SCALE;
                    float mn = fmaxf(m, sc);
                    float aa = __expf(m - mn);
                    float e  = __expf(sc - mn);
                    lsum = lsum*aa + e;
                    #pragma unroll
                    for (int d = 0; d < DHEAD; ++d)
                        acc[d] = acc[d]*aa + e * b2f(qkv[(size_t)(off+jj)*768 + 512 + h*32 + d]);
                    m = mn;
                }
                float inv = 1.0f / lsum;
                #pragma unroll
                for (int d = 0; d < DHEAD; ++d)
                    Ol[row*CPITCH + h*32 + d] = f2bf(acc[d]*inv);
            }
        }
        __syncthreads();   // Ol complete

        // ---- O @ WoT^T (block GEMM over K=256 in chunks of 64) ----
        f32x4 acc2[4][2] = {};
        for (int k0 = 0; k0 < 256; k0 += 64) {
            #pragma unroll
            for (int i = 0; i < 4; ++i) {
                int id = tid + i*512;
                int rown = id >> 3, seg = id & 7;
                *(ushort8*)&Bs[rown*72 + seg*8] =
                    *(const ushort8*)&WoT[(size_t)rown*FDIM + k0 + seg*8];
            }
            __syncthreads();
            #pragma unroll
            for (int kk = 0; kk < 64; kk += 32) {
                short8 a2[4], b2r[2];
                #pragma unroll
                for (int mi = 0; mi < 4; ++mi)
                    a2[mi] = *(const short8*)&Ol[(mi*16+lr)*CPITCH + k0 + kk + lk*8];
                #pragma unroll
                for (int ni = 0; ni < 2; ++ni)
                    b2r[ni] = *(const short8*)&Bs[(w*32 + ni*16 + lr)*72 + kk + lk*8];
                #pragma unroll
                for (int mi = 0; mi < 4; ++mi)
                    #pragma unroll
                    for (int ni = 0; ni < 2; ++ni)
                        acc2[mi][ni] = __builtin_amdgcn_mfma_f32_16x16x32_bf16(
                            a2[mi], b2r[ni], acc2[mi][ni], 0, 0, 0);
            }
            __syncthreads();
        }

        // ---- + bo + residual, LN over full row (cross-wave), write ----
        #pragma unroll
        for (int mi = 0; mi < 4; ++mi) {
            #pragma unroll
            for (int r = 0; r < 4; ++r) {
                int row = mi*16 + lk*4 + r;
                int srow = off + r0 + row;
                if (srow > PTS-1) srow = PTS-1;
                #pragma unroll
                for (int ni = 0; ni < 2; ++ni) {
                    int col = w*32 + ni*16 + lr;
                    acc2[mi][ni][r] += bo[col] + xs[(size_t)srow*FDIM + col];
                }
            }
        }
        #pragma unroll
        for (int mi = 0; mi < 4; ++mi) {
            #pragma unroll
            for (int r = 0; r < 4; ++r) {
                float ps = 0.f, pq = 0.f;
                #pragma unroll
                for (int ni = 0; ni < 2; ++ni) { float v = acc2[mi][ni][r]; ps += v; pq += v*v; }
                ps += __shfl_xor(ps, 1);  pq += __shfl_xor(pq, 1);
                ps += __shfl_xor(ps, 2);  pq += __shfl_xor(pq, 2);
                ps += __shfl_xor(ps, 4);  pq += __shfl_xor(pq, 4);
                ps += __shfl_xor(ps, 8);  pq += __shfl_xor(pq, 8);
                if (lr == 0) {
                    int row = mi*16 + lk*4 + r;
                    red_s[w*64 + row] = ps;
                    red_q[w*64 + row] = pq;
                }
            }
        }
        __syncthreads();
        #pragma unroll
        for (int mi = 0; mi < 4; ++mi) {
            #pragma unroll
            for (int r = 0; r < 4; ++r) {
                int row = mi*16 + lk*4 + r;
                float s = 0.f, q = 0.f;
                #pragma unroll
                for (int ww = 0; ww < 8; ++ww) { s += red_s[ww*64 + row]; q += red_q[ww*64 + row]; }
                float mu  = s * (1.0f/FDIM);
                float var = q * (1.0f/FDIM) - mu*mu;
                float rs  = rsqrtf(var + EPSF);
                if (row < nr) {
                    int srow = off + r0 + row;
                    #pragma unroll
                    for (int ni = 0; ni < 2; ++ni) {
                        int col = w*32 + ni*16 + lr;
                        float o = g[col]*(acc2[mi][ni][r]-mu)*rs + be[col];
                        x2[(size_t)srow*FDIM + col] = o;
                        x2b[(size_t)srow*FDIM + col] = f2bf(o);
                    }
                }
            }
        }
        __syncthreads();   // before next chunk overwrites Ol/red
    }
}

// ====== fused FFN: out = LN( relu(A@W1^T+b1)@W2^T + b2 + R ) =================
template<int FINAL>
__global__ __launch_bounds__(256) void ffn_k(
    const unsigned short* __restrict__ A,
    const unsigned short* __restrict__ W1T,
    const float* __restrict__ b1,
    const unsigned short* __restrict__ W2T,
    const float* __restrict__ b2,
    const float* __restrict__ R,
    const float* __restrict__ g, const float* __restrict__ be,
    const int* __restrict__ sorted,
    float* __restrict__ Cf, unsigned short* __restrict__ Cb)
{
    __shared__ unsigned short As[32*264];
    __shared__ unsigned short Bs1[64*264];
    __shared__ unsigned short Bs2[256*72];
    __shared__ unsigned short Hs[32*72];
    __shared__ float red_s[4][32], red_q[4][32];

    int tid = threadIdx.x;
    int l = tid & 63, wc = tid >> 6;
    int lr = l & 15, lk = l >> 4;
    int bm = blockIdx.x * 32;

    #pragma unroll
    for (int i = 0; i < 4; ++i) {
        int id = tid + i*256;
        int row = id >> 5, seg = id & 31;
        *(ushort8*)&As[row*264 + seg*8] =
            *(const ushort8*)&A[(size_t)(bm + row)*FDIM + seg*8];
    }

    f32x4 acc[2][4] = {};

    for (int hc = 0; hc < 8; ++hc) {
        __syncthreads();
        #pragma unroll
        for (int i = 0; i < 8; ++i) {
            int id = tid + i*256;
            int row = id >> 5, seg = id & 31;
            *(ushort8*)&Bs1[row*264 + seg*8] =
                *(const ushort8*)&W1T[(size_t)(hc*64 + row)*FDIM + seg*8];
        }
        #pragma unroll
        for (int i = 0; i < 8; ++i) {
            int id = tid + i*256;
            int row = id >> 3, seg = id & 7;
            *(ushort8*)&Bs2[row*72 + seg*8] =
                *(const ushort8*)&W2T[(size_t)row*HIDD + hc*64 + seg*8];
        }
        __syncthreads();

        f32x4 h[2] = {};
        #pragma unroll
        for (int kk = 0; kk < 256; kk += 32) {
            short8 bfr = *(const short8*)&Bs1[(wc*16 + lr)*264 + kk + lk*8];
            #pragma unroll
            for (int mi = 0; mi < 2; ++mi) {
                short8 a = *(const short8*)&As[(mi*16 + lr)*264 + kk + lk*8];
                h[mi] = __builtin_amdgcn_mfma_f32_16x16x32_bf16(a, bfr, h[mi], 0, 0, 0);
            }
        }
        #pragma unroll
        for (int mi = 0; mi < 2; ++mi)
            #pragma unroll
            for (int r = 0; r < 4; ++r) {
                int row = mi*16 + lk*4 + r;
                int hcol = wc*16 + lr;
                float v = h[mi][r] + b1[hc*64 + hcol];
                v = v > 0.f ? v : 0.f;
                Hs[row*72 + hcol] = f2bf(v);
            }
        __syncthreads();

        #pragma unroll
        for (int kk = 0; kk < 64; kk += 32) {
            short8 pa[2], wb[4];
            #pragma unroll
            for (int mi = 0; mi < 2; ++mi)
                pa[mi] = *(const short8*)&Hs[(mi*16 + lr)*72 + kk + lk*8];
            #pragma unroll
            for (int ni = 0; ni < 4; ++ni)
                wb[ni] = *(const short8*)&Bs2[(wc*64 + ni*16 + lr)*72 + kk + lk*8];
            #pragma unroll
            for (int mi = 0; mi < 2; ++mi)
                #pragma unroll
                for (int ni = 0; ni < 4; ++ni)
                    acc[mi][ni] = __builtin_amdgcn_mfma_f32_16x16x32_bf16(
                        pa[mi], wb[ni], acc[mi][ni], 0, 0, 0);
        }
    }

    #pragma unroll
    for (int mi = 0; mi < 2; ++mi) {
        #pragma unroll
        for (int r = 0; r < 4; ++r) {
            int row = bm + mi*16 + lk*4 + r;
            #pragma unroll
            for (int ni = 0; ni < 4; ++ni) {
                int col = wc*64 + ni*16 + lr;
                acc[mi][ni][r] += b2[col] + R[(size_t)row*FDIM + col];
            }
        }
    }
    #pragma unroll
    for (int mi = 0; mi < 2; ++mi) {
        #pragma unroll
        for (int r = 0; r < 4; ++r) {
            float ps = 0.f, pq = 0.f;
            #pragma unroll
            for (int ni = 0; ni < 4; ++ni) { float v = acc[mi][ni][r]; ps += v; pq += v*v; }
            ps += __shfl_xor(ps, 1);  pq += __shfl_xor(pq, 1);
            ps += __shfl_xor(ps, 2);  pq += __shfl_xor(pq, 2);
            ps += __shfl_xor(ps, 4);  pq += __shfl_xor(pq, 4);
            ps += __shfl_xor(ps, 8);  pq += __shfl_xor(pq, 8);
            if (lr == 0) {
                int rl = mi*16 + lk*4 + r;
                red_s[wc][rl] = ps;
                red_q[wc][rl] = pq;
            }
        }
    }
    __syncthreads();
    #pragma unroll
    for (int mi = 0; mi < 2; ++mi) {
        #pragma unroll
        for (int r = 0; r < 4; ++r) {
            int rl = mi*16 + lk*4 + r;
            float s = red_s[0][rl] + red_s[1][rl] + red_s[2][rl] + red_s[3][rl];
            float q = red_q[0][rl] + red_q[1][rl] + red_q[2][rl] + red_q[3][rl];
            float mu  = s * (1.0f/FDIM);
            float var = q * (1.0f/FDIM) - mu*mu;
            float rs  = rsqrtf(var + EPSF);
            int row = bm + rl;
            #pragma unroll
            for (int ni = 0; ni < 4; ++ni) {
                int col = wc*64 + ni*16 + lr;
                float o = g[col]*(acc[mi][ni][r]-mu)*rs + be[col];
                if (FINAL) Cf[(size_t)sorted[row]*FDIM + col] = o;
                else       Cf[(size_t)row*FDIM + col] = o;
                if (Cb) Cb[(size_t)row*FDIM + col] = f2bf(o);
            }
        }
    }
}

extern "C" void kernel_launch(void* const* d_in, const int* in_sizes, int n_in,
                              void* d_out, int out_size, void* d_ws, size_t ws_size,
                              hipStream_t stream)
{
    (void)in_sizes; (void)n_in; (void)out_size; (void)ws_size;
    const float* pos  = (const float*)d_in[0];
    const float* feat = (const float*)d_in[1];
    const float* kpts = (const float*)d_in[2];
    const float* kpw  = (const float*)d_in[3];
    const float* bn_g = (const float*)d_in[4];
    const float* bn_b = (const float*)d_in[5];
    const float* Wm   = (const float*)d_in[6];
    const float* Wq   = (const float*)d_in[7];
    const float* bq   = (const float*)d_in[8];
    const float* Wk   = (const float*)d_in[9];
    const float* bk   = (const float*)d_in[10];
    const float* Wv   = (const float*)d_in[11];
    const float* bv   = (const float*)d_in[12];
    const float* Wo   = (const float*)d_in[13];
    const float* bo   = (const float*)d_in[14];
    const float* g1   = (const float*)d_in[15];
    const float* be1  = (const float*)d_in[16];
    const float* W1   = (const float*)d_in[17];
    const float* bb1  = (const float*)d_in[18];
    const float* W2   = (const float*)d_in[19];
    const float* bb2  = (const float*)d_in[20];
    const float* g2   = (const float*)d_in[21];
    const float* be2  = (const float*)d_in[22];

    char* ws = (char*)d_ws;
    const size_t MB = 1024*1024;
    float* raw    = (float*)(ws + 0);                    // 2 MB
    unsigned long long* masks = (unsigned long long*)(ws + 2*MB);  // 2 MB
    float* stats  = (float*)(ws + 4*MB);                 // 512 B
    int*   hist   = (int*)(ws + 4*MB + 4096);            // 1 KB
    int*   offs   = hist + 256;
    int*   sorted = (int*)(ws + 4*MB + 16384);           // 32 KB
    int*   inv    = sorted + PTS;                        // 32 KB
    float* xs   = (float*)(ws + 5*MB);                   // [P,256] f32 (8 MB)
    float* x2   = (float*)(ws + 13*MB);                  // [P,256] f32 (8 MB)
    unsigned short* xsb   = (unsigned short*)(ws + 21*MB);  // [P,256] bf16 (4 MB)
    unsigned short* x2b   = (unsigned short*)(ws + 25*MB);  // [P,256] bf16 (4 MB)
    unsigned short* qkvb  = (unsigned short*)(ws + 29*MB);  // [P,768] bf16 (12 MB)
    unsigned short* wT    = (unsigned short*)(ws + 45*MB);  // 2 MB
    float*          bqkv  = (float*)(ws + 47*MB);           // 6 KB

    prep_k<<<3594, 256, 0, stream>>>(pos, Wq, Wk, Wv, Wo, W1, W2, bq, bk, bv,
                                     wT, bqkv, sorted, inv, offs, hist, masks);
    kpc_k<<<PTS/64, 256, 0, stream>>>(pos, feat, masks, kpts, kpw, raw);
    bn_stats_k<<<CKP, 256, 0, stream>>>(raw, stats);
    embed_k<<<PTS, 256, 0, stream>>>(pos, raw, stats, bn_g, bn_b, Wm, inv, xs, xsb);

    for (int l = 0; l < NLAY; ++l) {
        const unsigned short* W1T_l = wT + 524288 + (size_t)l*131072;
        const unsigned short* W2T_l = wT + 786432 + (size_t)l*131072;
        // fused QKV projection: [P,256] @ [256,768], 64-row tiles
        bgemm256_k<0,4><<<dim3(3, PTS/64), 256, 0, stream>>>(
            xsb, wT + (size_t)l*196608, bqkv + l*768, qkvb, 768, FDIM);
        // attention + O-proj + residual + LN1 -> x2/x2b
        attn2_k<<<dim3(64, BATCH), 512, 0, stream>>>(
            qkvb, wT + 393216 + (size_t)l*65536, bo + l*FDIM, xs,
            g1 + l*FDIM, be1 + l*FDIM, offs, hist, x2, x2b);
        // fused FFN + residual + LN2
        if (l == NLAY-1)
            ffn_k<1><<<PTS/32, 256, 0, stream>>>(
                x2b, W1T_l, bb1 + l*HIDD, W2T_l, bb2 + l*FDIM, x2,
                g2 + l*FDIM, be2 + l*FDIM, sorted, (float*)d_out, nullptr);
        else
            ffn_k<0><<<PTS/32, 256, 0, stream>>>(
                x2b, W1T_l, bb1 + l*HIDD, W2T_l, bb2 + l*FDIM, x2,
                g2 + l*FDIM, be2 + l*FDIM, nullptr, xs, xsb);
    }
}